// Round 1
// baseline (2651.259 us; speedup 1.0000x reference)
//
#include <hip/hip_runtime.h>

// GCN autoencoder: 8 x (GEMM + normalized graph aggregation), fp32.
// N=50000 nodes, E=800000 edges, F=500, H=256, C=10 (derived at runtime).

// ---------------------------------------------------------------- utility

__global__ void k_zero_int(int* __restrict__ p, int n) {
  int i = blockIdx.x * blockDim.x + threadIdx.x;
  if (i < n) p[i] = 0;
}

__global__ void k_copy_int(const int* __restrict__ a, int* __restrict__ b, int n) {
  int i = blockIdx.x * blockDim.x + threadIdx.x;
  if (i < n) b[i] = a[i];
}

__global__ void k_deg(const int* __restrict__ dst, int* __restrict__ deg, int E) {
  int i = blockIdx.x * blockDim.x + threadIdx.x;
  if (i < E) atomicAdd(&deg[dst[i]], 1);
}

__global__ void k_dinv(const int* __restrict__ deg, float* __restrict__ dinv, int n) {
  int i = blockIdx.x * blockDim.x + threadIdx.x;
  if (i < n) dinv[i] = rsqrtf((float)deg[i] + 1.0f);
}

// Single-block exclusive scan of deg[0..n) -> row_start[0..n], row_start[n]=total.
__global__ __launch_bounds__(1024) void k_scan(const int* __restrict__ deg,
                                               int* __restrict__ row_start, int n) {
  __shared__ int sh[1024];
  int t = threadIdx.x;
  int chunk = (n + 1023) / 1024;
  int lo = t * chunk;
  int hi = lo + chunk; if (hi > n) hi = n;
  int sum = 0;
  for (int i = lo; i < hi; ++i) sum += deg[i];
  sh[t] = sum;
  __syncthreads();
  for (int off = 1; off < 1024; off <<= 1) {
    int v = (t >= off) ? sh[t - off] : 0;
    __syncthreads();
    sh[t] += v;
    __syncthreads();
  }
  int run = sh[t] - sum;  // exclusive prefix of this thread's chunk
  for (int i = lo; i < hi; ++i) { row_start[i] = run; run += deg[i]; }
  if (t == 1023) row_start[n] = sh[1023];
}

__global__ void k_fill_csr(const int* __restrict__ src, const int* __restrict__ dst,
                           const float* __restrict__ dinv, int* __restrict__ cursor,
                           int* __restrict__ csr_src, float* __restrict__ csr_norm, int E) {
  int e = blockIdx.x * blockDim.x + threadIdx.x;
  if (e < E) {
    int d = dst[e];
    int s = src[e];
    int pos = atomicAdd(&cursor[d], 1);
    csr_src[pos] = s;
    csr_norm[pos] = dinv[s] * dinv[d];
  }
}

// ---------------------------------------------------------------- GEMM (fp32)
// C[M,Nd] = A[M,K] @ W[K,Nd]. Tile 64x64, K-tile 16, 256 threads, 4x4/thread.

#define BM 64
#define BN 64
#define BK 16

__global__ __launch_bounds__(256) void gemm_f32(const float* __restrict__ A,
                                                const float* __restrict__ W,
                                                float* __restrict__ C,
                                                int M, int K, int Nd) {
  __shared__ float As[BK][BM + 1];  // [k][m], +1 pad
  __shared__ float Ws[BK][BN];      // [k][n]
  const int bm = blockIdx.x * BM;
  const int bn = blockIdx.y * BN;
  const int tid = threadIdx.x;
  const int tx = tid & 15;        // 0..15 -> output col group
  const int ty = tid >> 4;        // 0..15 -> output row group
  float acc[4][4] = {};

  for (int k0 = 0; k0 < K; k0 += BK) {
    // A tile: 64 rows x 16 k. lane: kk = tid&15, row = tid>>4 (+16i)
    {
      int kk = tid & 15;
      int gk = k0 + kk;
      #pragma unroll
      for (int i = 0; i < 4; ++i) {
        int row = (tid >> 4) + 16 * i;
        int gm = bm + row;
        float v = 0.f;
        if (gm < M && gk < K) v = A[(long)gm * K + gk];
        As[kk][row] = v;
      }
    }
    // W tile: 16 k x 64 n. lane: c = tid&63, kw = tid>>6 (+4i)
    {
      int c = tid & 63;
      int gn = bn + c;
      #pragma unroll
      for (int i = 0; i < 4; ++i) {
        int kw = (tid >> 6) + 4 * i;
        int gk = k0 + kw;
        float v = 0.f;
        if (gk < K && gn < Nd) v = W[(long)gk * Nd + gn];
        Ws[kw][c] = v;
      }
    }
    __syncthreads();
    #pragma unroll
    for (int k = 0; k < BK; ++k) {
      float a[4], w[4];
      #pragma unroll
      for (int i = 0; i < 4; ++i) a[i] = As[k][ty + 16 * i];
      #pragma unroll
      for (int j = 0; j < 4; ++j) w[j] = Ws[k][tx + 16 * j];
      #pragma unroll
      for (int i = 0; i < 4; ++i)
        #pragma unroll
        for (int j = 0; j < 4; ++j)
          acc[i][j] = fmaf(a[i], w[j], acc[i][j]);
    }
    __syncthreads();
  }

  #pragma unroll
  for (int i = 0; i < 4; ++i) {
    int gm = bm + ty + 16 * i;
    if (gm >= M) continue;
    #pragma unroll
    for (int j = 0; j < 4; ++j) {
      int gn = bn + tx + 16 * j;
      if (gn < Nd) C[(long)gm * Nd + gn] = acc[i][j];
    }
  }
}

// ---------------------------------------------------------------- aggregation
// One block per dst node: out[i] = act( b + h[i]*dinv[i]^2 + sum_e h[src_e]*norm_e )

__global__ __launch_bounds__(256) void agg_kernel(const float* __restrict__ h,
                                                  const int* __restrict__ row_start,
                                                  const int* __restrict__ csr_src,
                                                  const float* __restrict__ csr_norm,
                                                  const float* __restrict__ dinv,
                                                  const float* __restrict__ bias,
                                                  float* __restrict__ out,
                                                  int N, int dout, int do_relu) {
  const int i = blockIdx.x;
  if (i >= N) return;
  const int tid = threadIdx.x;
  const int f0 = tid;
  const int f1 = tid + 256;
  if (f0 >= dout) return;  // no __syncthreads below; safe early exit
  const bool have1 = (f1 < dout);

  float sn = dinv[i];
  sn = sn * sn;
  const float* hi = h + (long)i * dout;
  float acc0 = bias[f0] + hi[f0] * sn;
  float acc1 = have1 ? (bias[f1] + hi[f1] * sn) : 0.f;

  const int s0 = row_start[i];
  const int s1 = row_start[i + 1];
  for (int s = s0; s < s1; ++s) {
    int src = csr_src[s];
    float w = csr_norm[s];
    const float* hs = h + (long)src * dout;
    acc0 = fmaf(hs[f0], w, acc0);
    if (have1) acc1 = fmaf(hs[f1], w, acc1);
  }
  if (do_relu) {
    acc0 = fmaxf(acc0, 0.f);
    acc1 = fmaxf(acc1, 0.f);
  }
  float* oi = out + (long)i * dout;
  oi[f0] = acc0;
  if (have1) oi[f1] = acc1;
}

// ---------------------------------------------------------------- driver

extern "C" void kernel_launch(void* const* d_in, const int* in_sizes, int n_in,
                              void* d_out, int out_size, void* d_ws, size_t ws_size,
                              hipStream_t stream) {
  const float* x   = (const float*)d_in[0];
  const int*   src = (const int*)d_in[1];
  const int*   dst = (const int*)d_in[2];
  const float* Wp[8];
  const float* bp[8];
  for (int i = 0; i < 8; ++i) {
    Wp[i] = (const float*)d_in[3 + 2 * i];
    bp[i] = (const float*)d_in[4 + 2 * i];
  }

  // Derive dims: H = |b_enc1|, F = |W_enc1|/H, N = |x|/F, E = |src|, C = |b_zen|
  const int H = in_sizes[4];
  const int F = in_sizes[3] / H;
  const int N = in_sizes[0] / F;
  const int E = in_sizes[1];
  const int C = in_sizes[10];

  // ---- workspace layout (16B aligned)
  char* ws = (char*)d_ws;
  size_t off = 0;
  auto alloc = [&](size_t bytes) {
    void* p = ws + off;
    off += (bytes + 255) & ~(size_t)255;
    return p;
  };
  int*   deg      = (int*)alloc((size_t)N * 4);
  int*   row_start= (int*)alloc((size_t)(N + 1) * 4);
  int*   cursor   = (int*)alloc((size_t)N * 4);
  float* dinv     = (float*)alloc((size_t)N * 4);
  int*   csr_src  = (int*)alloc((size_t)E * 4);
  float* csr_norm = (float*)alloc((size_t)E * 4);
  float* h_buf    = (float*)alloc((size_t)N * F * 4);   // max dout = F
  float* bufB     = (float*)alloc((size_t)N * H * 4);
  (void)ws_size;

  // ---- d_out layout: x_de[N,F] | enc_h1[N,H] | enc_h2[N,H] | enc_h3[N,H] | z_en[N,C]
  float* out_f   = (float*)d_out;
  float* o_xde   = out_f;
  float* o_enc1  = out_f + (size_t)N * F;
  float* o_enc2  = o_enc1 + (size_t)N * H;
  float* o_enc3  = o_enc2 + (size_t)N * H;
  float* o_zen   = o_enc3 + (size_t)N * H;
  // dec_h1 / dec_h3 scratch alias the (not-yet-final) x_de region.
  float* dec_h1  = o_xde;   // N*H floats, dead before x_de written
  float* dec_h3  = o_xde;   // consumed into h_buf by GEMM before agg writes x_de

  const int T = 256;
  // ---- graph preprocessing (per call; deterministic work)
  k_zero_int<<<(N + T - 1) / T, T, 0, stream>>>(deg, N);
  k_deg<<<(E + T - 1) / T, T, 0, stream>>>(dst, deg, E);
  k_dinv<<<(N + T - 1) / T, T, 0, stream>>>(deg, dinv, N);
  k_scan<<<1, 1024, 0, stream>>>(deg, row_start, N);
  k_copy_int<<<(N + T - 1) / T, T, 0, stream>>>(row_start, cursor, N);
  k_fill_csr<<<(E + T - 1) / T, T, 0, stream>>>(src, dst, dinv, cursor,
                                                csr_src, csr_norm, E);

  // ---- 8 conv layers
  struct Layer { const float* in; int K; int dout; float* out; int relu; int widx; };
  Layer layers[8] = {
    { x,      F, H, o_enc1, 1, 0 },  // enc1
    { o_enc1, H, H, o_enc2, 1, 1 },  // enc2
    { o_enc2, H, H, o_enc3, 1, 2 },  // enc3
    { o_enc3, H, C, o_zen,  0, 3 },  // zen
    { o_zen,  C, H, dec_h1, 1, 4 },  // dec1
    { dec_h1, H, H, bufB,   1, 5 },  // dec2
    { bufB,   H, H, dec_h3, 1, 6 },  // dec3
    { dec_h3, H, F, o_xde,  0, 7 },  // xde
  };

  for (int l = 0; l < 8; ++l) {
    const Layer& L = layers[l];
    dim3 grid((N + BM - 1) / BM, (L.dout + BN - 1) / BN);
    gemm_f32<<<grid, 256, 0, stream>>>(L.in, Wp[L.widx], h_buf, N, L.K, L.dout);
    agg_kernel<<<N, 256, 0, stream>>>(h_buf, row_start, csr_src, csr_norm,
                                      dinv, bp[L.widx], L.out, N, L.dout, L.relu);
  }
}

// Round 2
// 1060.986 us; speedup vs baseline: 2.4989x; 2.4989x over previous
//
#include <hip/hip_runtime.h>

// GCN autoencoder on MI355X: bf16-MFMA GEMMs + bf16 wave-per-node aggregation.
// N=50000, E=800000, F=500, H=256, C=10 (derived at runtime).

typedef __attribute__((ext_vector_type(8))) short short8;   // 8 x bf16 (4 VGPR)
typedef __attribute__((ext_vector_type(4))) float f32x4;    // MFMA accum

// ---------------------------------------------------------------- helpers

__device__ __forceinline__ float b2f(unsigned short u) {
  union { unsigned int i; float f; } v; v.i = ((unsigned int)u) << 16; return v.f;
}
__device__ __forceinline__ unsigned short f2b(float f) {  // round-to-nearest-even
  union { float f; unsigned int i; } v; v.f = f;
  unsigned int r = v.i + 0x7FFFu + ((v.i >> 16) & 1u);
  return (unsigned short)(r >> 16);
}

// ---------------------------------------------------------------- utility

__global__ void k_zero_int(int* __restrict__ p, int n) {
  int i = blockIdx.x * blockDim.x + threadIdx.x;
  if (i < n) p[i] = 0;
}

__global__ void k_copy_int(const int* __restrict__ a, int* __restrict__ b, int n) {
  int i = blockIdx.x * blockDim.x + threadIdx.x;
  if (i < n) b[i] = a[i];
}

__global__ void k_deg(const int* __restrict__ dst, int* __restrict__ deg, int E) {
  int i = blockIdx.x * blockDim.x + threadIdx.x;
  if (i < E) atomicAdd(&deg[dst[i]], 1);
}

__global__ void k_dinv(const int* __restrict__ deg, float* __restrict__ dinv, int n) {
  int i = blockIdx.x * blockDim.x + threadIdx.x;
  if (i < n) dinv[i] = rsqrtf((float)deg[i] + 1.0f);
}

// Single-block exclusive scan of deg[0..n) -> row_start[0..n], row_start[n]=total.
__global__ __launch_bounds__(1024) void k_scan(const int* __restrict__ deg,
                                               int* __restrict__ row_start, int n) {
  __shared__ int sh[1024];
  int t = threadIdx.x;
  int chunk = (n + 1023) / 1024;
  int lo = t * chunk;
  int hi = lo + chunk; if (hi > n) hi = n;
  int sum = 0;
  for (int i = lo; i < hi; ++i) sum += deg[i];
  sh[t] = sum;
  __syncthreads();
  for (int off = 1; off < 1024; off <<= 1) {
    int v = (t >= off) ? sh[t - off] : 0;
    __syncthreads();
    sh[t] += v;
    __syncthreads();
  }
  int run = sh[t] - sum;
  for (int i = lo; i < hi; ++i) { row_start[i] = run; run += deg[i]; }
  if (t == 1023) row_start[n] = sh[1023];
}

__global__ void k_fill_csr(const int* __restrict__ src, const int* __restrict__ dst,
                           const float* __restrict__ dinv, int* __restrict__ cursor,
                           int* __restrict__ csr_src, float* __restrict__ csr_norm, int E) {
  int e = blockIdx.x * blockDim.x + threadIdx.x;
  if (e < E) {
    int d = dst[e];
    int s = src[e];
    int pos = atomicAdd(&cursor[d], 1);
    csr_src[pos] = s;
    csr_norm[pos] = dinv[s] * dinv[d];
  }
}

// fp32 -> bf16 (vectorized)
__global__ void k_cvt(const float* __restrict__ in, unsigned short* __restrict__ out, long n) {
  long i = ((long)blockIdx.x * blockDim.x + threadIdx.x) * 4;
  if (i + 4 <= n) {
    float4 v = *(const float4*)&in[i];
    ushort4 o;
    o.x = f2b(v.x); o.y = f2b(v.y); o.z = f2b(v.z); o.w = f2b(v.w);
    *(ushort4*)&out[i] = o;
  } else {
    for (; i < n; ++i) out[i] = f2b(in[i]);
  }
}

// W[K][Nd] fp32 -> Wt[Nd][K] bf16
__global__ void k_wt(const float* __restrict__ W, unsigned short* __restrict__ Wt,
                     int K, int Nd) {
  int idx = blockIdx.x * blockDim.x + threadIdx.x;
  if (idx < K * Nd) {
    int k = idx / Nd, n = idx % Nd;
    Wt[(size_t)n * K + k] = f2b(W[idx]);
  }
}

// ---------------------------------------------------------------- GEMM (bf16 MFMA)
// C[M,Nd] = A[M,K] @ B[K,Nd], A bf16 row-major, Bt = B^T bf16 [Nd][K].
// 128x128 tile, 256 threads = 4 waves (2x2), each wave 64x64 via 4x4 frags of 16x16x32.
// Epilogue: optional bias, relu, fp32 and/or bf16 outputs.

__global__ __launch_bounds__(256) void gemm_bf16(
    const unsigned short* __restrict__ A,
    const unsigned short* __restrict__ Bt,
    const float* __restrict__ bias,     // nullable
    float* __restrict__ Cf,             // nullable
    unsigned short* __restrict__ Cb,    // nullable
    int M, int K, int Nd, int relu) {
  __shared__ unsigned short As[128][40];  // [m][k], +8 pad -> 80B stride (2-way only)
  __shared__ unsigned short Bs[128][40];  // [n][k], +8 pad

  const int bm = blockIdx.x * 128;
  const int bn = blockIdx.y * 128;
  const int tid = threadIdx.x;
  const int wid = tid >> 6;
  const int lane = tid & 63;
  const int wr = wid >> 1;        // wave row 0..1
  const int wc = wid & 1;         // wave col 0..1
  const int lrow = lane & 15;     // frag row (A) / col (B,D)
  const int kgrp = lane >> 4;     // k-subgroup 0..3

  f32x4 acc[4][4];
  #pragma unroll
  for (int i = 0; i < 4; ++i)
    #pragma unroll
    for (int j = 0; j < 4; ++j) acc[i][j] = (f32x4){0.f, 0.f, 0.f, 0.f};

  const int r  = tid >> 1;          // staging row 0..127
  const int c0 = (tid & 1) * 16;    // staging k-offset 0/16

  for (int k0 = 0; k0 < K; k0 += 32) {
    // ---- stage A tile [128][32]
    {
      int gm = bm + r;
      int gk = k0 + c0;
      unsigned short* dA = &As[r][c0];
      if (gm < M && gk + 16 <= K) {
        const unsigned int* gp = (const unsigned int*)(A + (size_t)gm * K + gk);
        unsigned int t0 = gp[0], t1 = gp[1], t2 = gp[2], t3 = gp[3];
        unsigned int t4 = gp[4], t5 = gp[5], t6 = gp[6], t7 = gp[7];
        uint4 w0; w0.x = t0; w0.y = t1; w0.z = t2; w0.w = t3;
        uint4 w1; w1.x = t4; w1.y = t5; w1.z = t6; w1.w = t7;
        *(uint4*)dA = w0;
        *(uint4*)(dA + 8) = w1;
      } else {
        #pragma unroll
        for (int e = 0; e < 16; ++e)
          dA[e] = (gm < M && gk + e < K) ? A[(size_t)gm * K + gk + e] : 0;
      }
    }
    // ---- stage B tile [128 n][32 k] from Bt[Nd][K]
    {
      int gn = bn + r;
      int gk = k0 + c0;
      unsigned short* dB = &Bs[r][c0];
      if (gn < Nd && gk + 16 <= K) {
        const unsigned int* gp = (const unsigned int*)(Bt + (size_t)gn * K + gk);
        unsigned int t0 = gp[0], t1 = gp[1], t2 = gp[2], t3 = gp[3];
        unsigned int t4 = gp[4], t5 = gp[5], t6 = gp[6], t7 = gp[7];
        uint4 w0; w0.x = t0; w0.y = t1; w0.z = t2; w0.w = t3;
        uint4 w1; w1.x = t4; w1.y = t5; w1.z = t6; w1.w = t7;
        *(uint4*)dB = w0;
        *(uint4*)(dB + 8) = w1;
      } else {
        #pragma unroll
        for (int e = 0; e < 16; ++e)
          dB[e] = (gn < Nd && gk + e < K) ? Bt[(size_t)gn * K + gk + e] : 0;
      }
    }
    __syncthreads();

    short8 a[4], b[4];
    #pragma unroll
    for (int mi = 0; mi < 4; ++mi)
      a[mi] = *(const short8*)&As[wr * 64 + mi * 16 + lrow][kgrp * 8];
    #pragma unroll
    for (int nj = 0; nj < 4; ++nj)
      b[nj] = *(const short8*)&Bs[wc * 64 + nj * 16 + lrow][kgrp * 8];
    #pragma unroll
    for (int mi = 0; mi < 4; ++mi)
      #pragma unroll
      for (int nj = 0; nj < 4; ++nj)
        acc[mi][nj] = __builtin_amdgcn_mfma_f32_16x16x32_bf16(a[mi], b[nj], acc[mi][nj], 0, 0, 0);

    __syncthreads();
  }

  // ---- epilogue: D row = 4*kgrp + reg, col = lrow (within 16x16 frag)
  const int orow = bm + wr * 64;
  const int ocol = bn + wc * 64;
  #pragma unroll
  for (int mi = 0; mi < 4; ++mi) {
    #pragma unroll
    for (int rr = 0; rr < 4; ++rr) {
      int gm = orow + mi * 16 + 4 * kgrp + rr;
      if (gm >= M) continue;
      size_t rowoff = (size_t)gm * Nd;
      #pragma unroll
      for (int nj = 0; nj < 4; ++nj) {
        int gn = ocol + nj * 16 + lrow;
        if (gn >= Nd) continue;
        float v = acc[mi][nj][rr];
        if (bias) v += bias[gn];
        if (relu) v = fmaxf(v, 0.f);
        if (Cf) Cf[rowoff + gn] = v;
        if (Cb) Cb[rowoff + gn] = f2b(v);
      }
    }
  }
}

// ---------------------------------------------------------------- aggregation
// Wave per node (4 nodes/block), lane handles 4 consecutive features (dout==256 path).
// out[i] = act( [b +] h[i]*dinv[i]^2 + sum_e h[src_e]*norm_e )

__global__ __launch_bounds__(256) void agg_wave(
    const unsigned short* __restrict__ h,
    const int* __restrict__ row_start, const int* __restrict__ csr_src,
    const float* __restrict__ csr_norm, const float* __restrict__ dinv,
    const float* __restrict__ bias,       // nullable
    float* __restrict__ Of,               // nullable
    unsigned short* __restrict__ Ob,      // nullable
    int N, int dout, int relu) {
  const int w = threadIdx.x >> 6;
  const int lane = threadIdx.x & 63;
  const int i = blockIdx.x * 4 + w;
  if (i >= N) return;
  const int f0 = lane * 4;
  if (f0 >= dout) return;

  float sn = dinv[i];
  sn = sn * sn;
  ushort4 hv = *(const ushort4*)(h + (size_t)i * dout + f0);
  float a0 = b2f(hv.x) * sn, a1 = b2f(hv.y) * sn, a2 = b2f(hv.z) * sn, a3 = b2f(hv.w) * sn;
  if (bias) {
    float4 bv = *(const float4*)&bias[f0];
    a0 += bv.x; a1 += bv.y; a2 += bv.z; a3 += bv.w;
  }

  const int s0 = row_start[i];
  const int s1 = row_start[i + 1];
  int s = s0;
  for (; s + 1 < s1; s += 2) {
    int src0 = csr_src[s];     float w0 = csr_norm[s];
    int src1 = csr_src[s + 1]; float w1 = csr_norm[s + 1];
    ushort4 v0 = *(const ushort4*)(h + (size_t)src0 * dout + f0);
    ushort4 v1 = *(const ushort4*)(h + (size_t)src1 * dout + f0);
    a0 = fmaf(b2f(v0.x), w0, a0); a1 = fmaf(b2f(v0.y), w0, a1);
    a2 = fmaf(b2f(v0.z), w0, a2); a3 = fmaf(b2f(v0.w), w0, a3);
    a0 = fmaf(b2f(v1.x), w1, a0); a1 = fmaf(b2f(v1.y), w1, a1);
    a2 = fmaf(b2f(v1.z), w1, a2); a3 = fmaf(b2f(v1.w), w1, a3);
  }
  if (s < s1) {
    int src0 = csr_src[s]; float w0 = csr_norm[s];
    ushort4 v0 = *(const ushort4*)(h + (size_t)src0 * dout + f0);
    a0 = fmaf(b2f(v0.x), w0, a0); a1 = fmaf(b2f(v0.y), w0, a1);
    a2 = fmaf(b2f(v0.z), w0, a2); a3 = fmaf(b2f(v0.w), w0, a3);
  }
  if (relu) {
    a0 = fmaxf(a0, 0.f); a1 = fmaxf(a1, 0.f); a2 = fmaxf(a2, 0.f); a3 = fmaxf(a3, 0.f);
  }
  size_t o = (size_t)i * dout + f0;
  if (Of) {
    float4 ov; ov.x = a0; ov.y = a1; ov.z = a2; ov.w = a3;
    *(float4*)&Of[o] = ov;
  }
  if (Ob) {
    ushort4 ob; ob.x = f2b(a0); ob.y = f2b(a1); ob.z = f2b(a2); ob.w = f2b(a3);
    *(ushort4*)&Ob[o] = ob;
  }
}

// Thread-per-node aggregation for small dout (<=16).
__global__ void agg_small(
    const unsigned short* __restrict__ h,
    const int* __restrict__ row_start, const int* __restrict__ csr_src,
    const float* __restrict__ csr_norm, const float* __restrict__ dinv,
    const float* __restrict__ bias, float* __restrict__ Of,
    unsigned short* __restrict__ Ob, int N, int dout, int relu) {
  const int i = blockIdx.x * blockDim.x + threadIdx.x;
  if (i >= N) return;
  float acc[16];
  float sn = dinv[i];
  sn = sn * sn;
  const unsigned short* hi = h + (size_t)i * dout;
  for (int f = 0; f < dout; ++f)
    acc[f] = b2f(hi[f]) * sn + (bias ? bias[f] : 0.f);
  const int s0 = row_start[i];
  const int s1 = row_start[i + 1];
  for (int s = s0; s < s1; ++s) {
    const unsigned short* hs = h + (size_t)csr_src[s] * dout;
    float w = csr_norm[s];
    for (int f = 0; f < dout; ++f) acc[f] = fmaf(b2f(hs[f]), w, acc[f]);
  }
  for (int f = 0; f < dout; ++f) {
    float v = acc[f];
    if (relu) v = fmaxf(v, 0.f);
    if (Of) Of[(size_t)i * dout + f] = v;
    if (Ob) Ob[(size_t)i * dout + f] = f2b(v);
  }
}

// ---------------------------------------------------------------- driver

extern "C" void kernel_launch(void* const* d_in, const int* in_sizes, int n_in,
                              void* d_out, int out_size, void* d_ws, size_t ws_size,
                              hipStream_t stream) {
  const float* x   = (const float*)d_in[0];
  const int*   src = (const int*)d_in[1];
  const int*   dst = (const int*)d_in[2];
  const float* Wp[8];
  const float* bp[8];
  for (int i = 0; i < 8; ++i) {
    Wp[i] = (const float*)d_in[3 + 2 * i];
    bp[i] = (const float*)d_in[4 + 2 * i];
  }

  const int H = in_sizes[4];
  const int F = in_sizes[3] / H;
  const int N = in_sizes[0] / F;
  const int E = in_sizes[1];
  const int C = in_sizes[10];

  // layer dims: din, dout
  const int dims[8][2] = { {F,H},{H,H},{H,H},{H,C},{C,H},{H,H},{H,H},{H,F} };

  // ---- workspace layout (256B aligned)
  char* ws = (char*)d_ws;
  size_t off = 0;
  auto alloc = [&](size_t bytes) {
    void* p = ws + off;
    off += (bytes + 255) & ~(size_t)255;
    return p;
  };
  int*   deg       = (int*)alloc((size_t)N * 4);
  int*   row_start = (int*)alloc((size_t)(N + 1) * 4);
  int*   cursor    = (int*)alloc((size_t)N * 4);
  float* dinv      = (float*)alloc((size_t)N * 4);
  int*   csr_src   = (int*)alloc((size_t)E * 4);
  float* csr_norm  = (float*)alloc((size_t)E * 4);
  unsigned short* xb   = (unsigned short*)alloc((size_t)N * F * 2);
  unsigned short* Wt[8];
  for (int i = 0; i < 8; ++i)
    Wt[i] = (unsigned short*)alloc((size_t)dims[i][0] * dims[i][1] * 2);
  unsigned short* hb   = (unsigned short*)alloc((size_t)N * H * 2);
  unsigned short* actP = (unsigned short*)alloc((size_t)N * H * 2);
  unsigned short* actQ = (unsigned short*)alloc((size_t)N * H * 2);
  unsigned short* zb   = (unsigned short*)alloc((size_t)N * C * 2);
  unsigned short* zagg = (unsigned short*)alloc((size_t)N * C * 2);
  (void)ws_size;

  // ---- d_out layout: x_de[N,F] | enc_h1[N,H] | enc_h2[N,H] | enc_h3[N,H] | z_en[N,C]
  float* out_f  = (float*)d_out;
  float* o_xde  = out_f;
  float* o_enc1 = out_f + (size_t)N * F;
  float* o_enc2 = o_enc1 + (size_t)N * H;
  float* o_enc3 = o_enc2 + (size_t)N * H;
  float* o_zen  = o_enc3 + (size_t)N * H;

  const int T = 256;
  // ---- graph preprocessing
  k_zero_int<<<(N + T - 1) / T, T, 0, stream>>>(deg, N);
  k_deg<<<(E + T - 1) / T, T, 0, stream>>>(dst, deg, E);
  k_dinv<<<(N + T - 1) / T, T, 0, stream>>>(deg, dinv, N);
  k_scan<<<1, 1024, 0, stream>>>(deg, row_start, N);
  k_copy_int<<<(N + T - 1) / T, T, 0, stream>>>(row_start, cursor, N);
  k_fill_csr<<<(E + T - 1) / T, T, 0, stream>>>(src, dst, dinv, cursor,
                                                csr_src, csr_norm, E);
  // ---- input/weight conversion
  {
    long nx = (long)N * F;
    k_cvt<<<(int)((nx / 4 + T - 1) / T), T, 0, stream>>>(x, xb, nx);
    for (int i = 0; i < 8; ++i) {
      int kn = dims[i][0] * dims[i][1];
      k_wt<<<(kn + T - 1) / T, T, 0, stream>>>(Wp[i], Wt[i], dims[i][0], dims[i][1]);
    }
  }

  auto gemm = [&](const unsigned short* A, int widx, const float* bias,
                  float* Cf, unsigned short* Cb, int K, int Nd, int relu) {
    dim3 grid((N + 127) / 128, (Nd + 127) / 128);
    gemm_bf16<<<grid, 256, 0, stream>>>(A, Wt[widx], bias, Cf, Cb, N, K, Nd, relu);
  };
  auto agg256 = [&](const unsigned short* h, const float* bias, float* Of,
                    unsigned short* Ob, int relu) {
    agg_wave<<<(N + 3) / 4, 256, 0, stream>>>(h, row_start, csr_src, csr_norm,
                                              dinv, bias, Of, Ob, N, H, relu);
  };
  auto aggC = [&](const unsigned short* h, const float* bias, float* Of,
                  unsigned short* Ob, int relu) {
    agg_small<<<(N + T - 1) / T, T, 0, stream>>>(h, row_start, csr_src, csr_norm,
                                                 dinv, bias, Of, Ob, N, C, relu);
  };

  // enc1: h = xb @ W0 ; enc_h1 = relu(agg(h)+b0)
  gemm(xb, 0, nullptr, nullptr, hb, F, H, 0);
  agg256(hb, bp[0], o_enc1, actP, 1);
  // enc2
  gemm(actP, 1, nullptr, nullptr, hb, H, H, 0);
  agg256(hb, bp[1], o_enc2, actQ, 1);
  // enc3
  gemm(actQ, 2, nullptr, nullptr, hb, H, H, 0);
  agg256(hb, bp[2], o_enc3, actP, 1);
  // zen: h = a3 @ W3 (N x C) ; z_en = agg(h)+b3
  gemm(actP, 3, nullptr, nullptr, hb, H, C, 0);
  aggC(hb, bp[3], o_zen, zb, 0);
  // dec1 (reordered): zagg = agg_nobias(z) ; d1 = relu(zagg @ W4 + b4)
  aggC(zb, nullptr, nullptr, zagg, 0);
  gemm(zagg, 4, bp[4], nullptr, actQ, C, H, 1);
  // dec2
  gemm(actQ, 5, nullptr, nullptr, hb, H, H, 0);
  agg256(hb, bp[5], nullptr, actP, 1);
  // dec3
  gemm(actP, 6, nullptr, nullptr, hb, H, H, 0);
  agg256(hb, bp[6], nullptr, actQ, 1);
  // xde (reordered): dagg = agg_nobias(d3) ; x_de = dagg @ W7 + b7 (fp32 direct)
  agg256(actQ, nullptr, nullptr, actP, 0);
  gemm(actP, 7, bp[7], o_xde, nullptr, H, F, 0);
}

// Round 3
// 960.209 us; speedup vs baseline: 2.7611x; 1.1050x over previous
//
#include <hip/hip_runtime.h>

// GCN autoencoder on MI355X (gfx950).
// bf16-MFMA GEMM w/ global_load_lds + swizzle, bf16 gather aggregation.
// N=50000, E=800000, F=500, H=256, C=10 (derived at runtime).

typedef __attribute__((ext_vector_type(8))) short short8;           // 8 bf16
typedef __attribute__((ext_vector_type(4))) float f32x4;            // MFMA acc
typedef __attribute__((ext_vector_type(4))) unsigned short u16x4;   // 4 bf16

// ---------------------------------------------------------------- helpers

__device__ __forceinline__ float b2f(unsigned short u) {
  union { unsigned int i; float f; } v; v.i = ((unsigned int)u) << 16; return v.f;
}
__device__ __forceinline__ unsigned short f2b(float f) {  // RNE
  union { float f; unsigned int i; } v; v.f = f;
  unsigned int r = v.i + 0x7FFFu + ((v.i >> 16) & 1u);
  return (unsigned short)(r >> 16);
}

// async global->LDS, 16B per lane; dest = lds_base(wave-uniform) + lane*16
__device__ __forceinline__ void gload16(const void* g, void* l) {
  __builtin_amdgcn_global_load_lds(
      (const __attribute__((address_space(1))) unsigned int*)g,
      (__attribute__((address_space(3))) unsigned int*)l, 16, 0, 0);
}

// ---------------------------------------------------------------- preproc

__global__ void k_zero_int(int* __restrict__ p, int n) {
  int i = blockIdx.x * blockDim.x + threadIdx.x;
  if (i < n) p[i] = 0;
}

__global__ void k_deg(const int* __restrict__ dst, int* __restrict__ deg, int E) {
  int i = blockIdx.x * blockDim.x + threadIdx.x;
  if (i < E) atomicAdd(&deg[dst[i]], 1);
}

// single-block: exclusive scan -> row_start & cursor; also dinv = rsqrt(deg+1)
__global__ __launch_bounds__(1024) void k_scan_all(const int* __restrict__ deg,
                                                   int* __restrict__ row_start,
                                                   int* __restrict__ cursor,
                                                   float* __restrict__ dinv, int n) {
  __shared__ int sh[1024];
  int t = threadIdx.x;
  int chunk = (n + 1023) / 1024;
  int lo = t * chunk;
  int hi = lo + chunk; if (hi > n) hi = n;
  int sum = 0;
  for (int i = lo; i < hi; ++i) sum += deg[i];
  sh[t] = sum;
  __syncthreads();
  for (int off = 1; off < 1024; off <<= 1) {
    int v = (t >= off) ? sh[t - off] : 0;
    __syncthreads();
    sh[t] += v;
    __syncthreads();
  }
  int run = sh[t] - sum;
  for (int i = lo; i < hi; ++i) {
    row_start[i] = run;
    cursor[i] = run;
    dinv[i] = rsqrtf((float)deg[i] + 1.0f);
    run += deg[i];
  }
  if (t == 1023) row_start[n] = sh[1023];
}

__global__ void k_fill_csr(const int* __restrict__ src, const int* __restrict__ dst,
                           const float* __restrict__ dinv, int* __restrict__ cursor,
                           int* __restrict__ csr_src, float* __restrict__ csr_norm, int E) {
  int e = blockIdx.x * blockDim.x + threadIdx.x;
  if (e < E) {
    int d = dst[e];
    int s = src[e];
    int pos = atomicAdd(&cursor[d], 1);
    csr_src[pos] = s;
    csr_norm[pos] = dinv[s] * dinv[d];
  }
}

// x[N][F] fp32 -> xb[N][Fp] bf16, zero-padded cols
__global__ void k_cvt_pad(const float* __restrict__ in, unsigned short* __restrict__ out,
                          int N, int F, int Fp) {
  int idx = blockIdx.x * blockDim.x + threadIdx.x;  // one per 8 outputs
  int perRow = Fp >> 3;
  int row = idx / perRow;
  int c = (idx - row * perRow) << 3;
  if (row >= N) return;
  unsigned short o[8];
  if (c + 8 <= F) {
    const float* p = in + (size_t)row * F + c;
    #pragma unroll
    for (int e = 0; e < 8; ++e) o[e] = f2b(p[e]);
  } else {
    #pragma unroll
    for (int e = 0; e < 8; ++e) {
      int cc = c + e;
      o[e] = (cc < F) ? f2b(in[(size_t)row * F + cc]) : (unsigned short)0;
    }
  }
  *(short8*)(out + (size_t)row * Fp + c) = *(short8*)o;
}

// all 8 weights: W[K][Nd] fp32 -> Wt[Ndp][Kp] bf16 (transposed, zero-padded)
struct WtPack {
  const float* W[8];
  unsigned short* Wt[8];
  int K[8], Nd[8], Kp[8], Ndp[8];
};

__global__ void k_wt_all(WtPack p) {
  int l = blockIdx.y;
  int idx = blockIdx.x * blockDim.x + threadIdx.x;
  int Kp = p.Kp[l], Ndp = p.Ndp[l];
  if (idx >= Kp * Ndp) return;
  int n = idx / Kp, k = idx - n * Kp;
  unsigned short v = 0;
  if (n < p.Nd[l] && k < p.K[l]) v = f2b(p.W[l][(size_t)k * p.Nd[l] + n]);
  p.Wt[l][idx] = v;
}

// ---------------------------------------------------------------- GEMM
// C[M,Nd] = A[M,Kp] @ Bt^T, A bf16 [M][lda] (K zero-padded), Bt bf16 [Ndp][Kp]
// (fully padded: Ndp %128==0, Kp %32==0). 128x128 tile, 4 waves (2x2), 4x4
// frags of mfma_f32_16x16x32_bf16. global_load_lds staging, double-buffered,
// slot-swizzle (slot ^= (row>>1)&3) applied at global source AND ds_read.

__global__ __launch_bounds__(256) void gemm_bf16(
    const unsigned short* __restrict__ A,
    const unsigned short* __restrict__ Bt,
    const float* __restrict__ bias,     // nullable, [Nd]
    float* __restrict__ Cf, int ldcf,   // nullable
    unsigned short* __restrict__ Cb, int ldcb,  // nullable
    int M, int Kp, int Nd, int lda, int relu) {
  __shared__ unsigned short As[2][4096];  // 128 rows x 32 bf16 (64B rows)
  __shared__ unsigned short Bs[2][4096];

  const int bm = blockIdx.x * 128;
  const int bn = blockIdx.y * 128;
  const int tid = threadIdx.x;
  const int wid = tid >> 6;
  const int lane = tid & 63;

  // ---- staging source addresses (2 chunks of 1024B per wave per tile)
  const unsigned short* srcA[2];
  const unsigned short* srcB[2];
  #pragma unroll
  for (int j = 0; j < 2; ++j) {
    int chunk = wid * 2 + j;
    int r_st = chunk * 16 + (lane >> 2);    // tile row this lane fills
    int slot = lane & 3;                    // 16B slot within 64B row
    int sw = slot ^ ((r_st >> 1) & 3);      // swizzled source slot
    int gm = bm + r_st; if (gm > M - 1) gm = M - 1;   // clamp: dup rows unused
    srcA[j] = A + (size_t)gm * lda + sw * 8;
    int gn = bn + r_st;                     // always < Ndp (padded)
    srcB[j] = Bt + (size_t)gn * Kp + sw * 8;
  }

  // ---- fragment read offsets (elements), swizzle matches staging
  const int wr = wid >> 1, wc = wid & 1;
  const int lrow = lane & 15;
  const int kgrp = lane >> 4;
  const int rA = wr * 64 + lrow;
  const int rB = wc * 64 + lrow;
  const int aoff = rA * 32 + (kgrp ^ ((rA >> 1) & 3)) * 8;
  const int boff = rB * 32 + (kgrp ^ ((rB >> 1) & 3)) * 8;

  f32x4 acc[4][4];
  #pragma unroll
  for (int i = 0; i < 4; ++i)
    #pragma unroll
    for (int j = 0; j < 4; ++j) acc[i][j] = (f32x4){0.f, 0.f, 0.f, 0.f};

  auto stage = [&](int buf, int k0) {
    #pragma unroll
    for (int j = 0; j < 2; ++j) {
      int chunk = wid * 2 + j;
      gload16(srcA[j] + k0, &As[buf][chunk * 512]);
      gload16(srcB[j] + k0, &Bs[buf][chunk * 512]);
    }
  };

  const int nt = Kp >> 5;
  stage(0, 0);
  __syncthreads();   // drains vmcnt -> buf0 ready
  int cur = 0;
  for (int t = 0; t < nt; ++t) {
    if (t + 1 < nt) stage(cur ^ 1, (t + 1) * 32);
    const unsigned short* pA = &As[cur][aoff];
    const unsigned short* pB = &Bs[cur][boff];
    short8 a[4], b[4];
    #pragma unroll
    for (int mi = 0; mi < 4; ++mi) a[mi] = *(const short8*)(pA + mi * 512);
    #pragma unroll
    for (int nj = 0; nj < 4; ++nj) b[nj] = *(const short8*)(pB + nj * 512);
    #pragma unroll
    for (int mi = 0; mi < 4; ++mi)
      #pragma unroll
      for (int nj = 0; nj < 4; ++nj)
        acc[mi][nj] = __builtin_amdgcn_mfma_f32_16x16x32_bf16(a[mi], b[nj], acc[mi][nj], 0, 0, 0);
    __syncthreads();  // staged buf done (vmcnt0) + all reads of cur done
    cur ^= 1;
  }

  // ---- epilogue: frag D row = 4*kgrp + rr, col = lrow
  const int orow = bm + wr * 64;
  const int ocol = bn + wc * 64;
  float bv[4];
  #pragma unroll
  for (int nj = 0; nj < 4; ++nj) {
    int gn = ocol + nj * 16 + lrow;
    bv[nj] = (bias && gn < Nd) ? bias[gn] : 0.f;
  }
  #pragma unroll
  for (int mi = 0; mi < 4; ++mi) {
    #pragma unroll
    for (int rr = 0; rr < 4; ++rr) {
      int gm = orow + mi * 16 + 4 * kgrp + rr;
      if (gm >= M) continue;
      #pragma unroll
      for (int nj = 0; nj < 4; ++nj) {
        int gn = ocol + nj * 16 + lrow;
        if (gn >= Nd) continue;
        float v = acc[mi][nj][rr] + bv[nj];
        if (relu) v = fmaxf(v, 0.f);
        if (Cf) Cf[(size_t)gm * ldcf + gn] = v;
        if (Cb) Cb[(size_t)gm * ldcb + gn] = f2b(v);
      }
    }
  }
}

// ---------------------------------------------------------------- aggregation
// Wave per node, lane = 4 consecutive features (dout fixed 256).
// out[i] = act( [b +] h[i]*dinv[i]^2 + sum_e h[src_e]*norm_e )

__global__ __launch_bounds__(256) void agg_wave(
    const unsigned short* __restrict__ h,
    const int* __restrict__ row_start, const int* __restrict__ csr_src,
    const float* __restrict__ csr_norm, const float* __restrict__ dinv,
    const float* __restrict__ bias,      // nullable
    float* __restrict__ Of,              // nullable
    unsigned short* __restrict__ Ob,     // nullable
    int N, int relu) {
  const int w = threadIdx.x >> 6;
  const int lane = threadIdx.x & 63;
  const int i = blockIdx.x * 4 + w;
  if (i >= N) return;
  const int f0 = lane * 4;

  float sn = dinv[i];
  sn = sn * sn;
  u16x4 hv = *(const u16x4*)(h + ((size_t)i << 8) + f0);
  float a0 = b2f(hv.x) * sn, a1 = b2f(hv.y) * sn;
  float a2 = b2f(hv.z) * sn, a3 = b2f(hv.w) * sn;
  if (bias) {
    f32x4 bv = *(const f32x4*)(bias + f0);
    a0 += bv.x; a1 += bv.y; a2 += bv.z; a3 += bv.w;
  }

  int s = row_start[i];
  const int s1 = row_start[i + 1];
  for (; s + 4 <= s1; s += 4) {
    int p0 = csr_src[s], p1 = csr_src[s + 1], p2 = csr_src[s + 2], p3 = csr_src[s + 3];
    float w0 = csr_norm[s], w1 = csr_norm[s + 1], w2 = csr_norm[s + 2], w3 = csr_norm[s + 3];
    u16x4 v0 = *(const u16x4*)(h + ((size_t)p0 << 8) + f0);
    u16x4 v1 = *(const u16x4*)(h + ((size_t)p1 << 8) + f0);
    u16x4 v2 = *(const u16x4*)(h + ((size_t)p2 << 8) + f0);
    u16x4 v3 = *(const u16x4*)(h + ((size_t)p3 << 8) + f0);
    a0 = fmaf(b2f(v0.x), w0, a0); a1 = fmaf(b2f(v0.y), w0, a1);
    a2 = fmaf(b2f(v0.z), w0, a2); a3 = fmaf(b2f(v0.w), w0, a3);
    a0 = fmaf(b2f(v1.x), w1, a0); a1 = fmaf(b2f(v1.y), w1, a1);
    a2 = fmaf(b2f(v1.z), w1, a2); a3 = fmaf(b2f(v1.w), w1, a3);
    a0 = fmaf(b2f(v2.x), w2, a0); a1 = fmaf(b2f(v2.y), w2, a1);
    a2 = fmaf(b2f(v2.z), w2, a2); a3 = fmaf(b2f(v2.w), w2, a3);
    a0 = fmaf(b2f(v3.x), w3, a0); a1 = fmaf(b2f(v3.y), w3, a1);
    a2 = fmaf(b2f(v3.z), w3, a2); a3 = fmaf(b2f(v3.w), w3, a3);
  }
  for (; s < s1; ++s) {
    int p0 = csr_src[s];
    float w0 = csr_norm[s];
    u16x4 v0 = *(const u16x4*)(h + ((size_t)p0 << 8) + f0);
    a0 = fmaf(b2f(v0.x), w0, a0); a1 = fmaf(b2f(v0.y), w0, a1);
    a2 = fmaf(b2f(v0.z), w0, a2); a3 = fmaf(b2f(v0.w), w0, a3);
  }
  if (relu) {
    a0 = fmaxf(a0, 0.f); a1 = fmaxf(a1, 0.f);
    a2 = fmaxf(a2, 0.f); a3 = fmaxf(a3, 0.f);
  }
  size_t o = ((size_t)i << 8) + f0;
  if (Of) {
    f32x4 ov; ov.x = a0; ov.y = a1; ov.z = a2; ov.w = a3;
    __builtin_nontemporal_store(ov, (f32x4*)(Of + o));
  }
  if (Ob) {
    u16x4 ob; ob.x = f2b(a0); ob.y = f2b(a1); ob.z = f2b(a2); ob.w = f2b(a3);
    __builtin_nontemporal_store(ob, (u16x4*)(Ob + o));
  }
}

// Thread-per-node aggregation, compile-time width CD (for C=10 code layers).
template <int CD>
__global__ void agg_small_t(
    const unsigned short* __restrict__ h, int ldh,
    const int* __restrict__ row_start, const int* __restrict__ csr_src,
    const float* __restrict__ csr_norm, const float* __restrict__ dinv,
    const float* __restrict__ bias, float* __restrict__ Of,
    unsigned short* __restrict__ Ob, int ldo, int N) {
  const int i = blockIdx.x * blockDim.x + threadIdx.x;
  if (i >= N) return;
  float acc[CD];
  float sn = dinv[i];
  sn = sn * sn;
  const unsigned short* hi = h + (size_t)i * ldh;
  #pragma unroll
  for (int f = 0; f < CD; ++f) acc[f] = b2f(hi[f]) * sn + (bias ? bias[f] : 0.f);
  const int s1 = row_start[i + 1];
  for (int s = row_start[i]; s < s1; ++s) {
    const unsigned short* hs = h + (size_t)csr_src[s] * ldh;
    float wgt = csr_norm[s];
    #pragma unroll
    for (int f = 0; f < CD; ++f) acc[f] = fmaf(b2f(hs[f]), wgt, acc[f]);
  }
  if (Of) {
    #pragma unroll
    for (int f = 0; f < CD; ++f) Of[(size_t)i * CD + f] = acc[f];
  }
  if (Ob) {
    #pragma unroll
    for (int f = 0; f < CD; ++f) Ob[(size_t)i * ldo + f] = f2b(acc[f]);
    for (int f = CD; f < ldo; ++f) Ob[(size_t)i * ldo + f] = 0;
  }
}

// ---------------------------------------------------------------- driver

extern "C" void kernel_launch(void* const* d_in, const int* in_sizes, int n_in,
                              void* d_out, int out_size, void* d_ws, size_t ws_size,
                              hipStream_t stream) {
  const float* x   = (const float*)d_in[0];
  const int*   src = (const int*)d_in[1];
  const int*   dst = (const int*)d_in[2];
  const float* Wp[8];
  const float* bp[8];
  for (int i = 0; i < 8; ++i) {
    Wp[i] = (const float*)d_in[3 + 2 * i];
    bp[i] = (const float*)d_in[4 + 2 * i];
  }

  const int H = in_sizes[4];
  const int F = in_sizes[3] / H;
  const int N = in_sizes[0] / F;
  const int E = in_sizes[1];
  const int C = in_sizes[10];

  const int Fp = (F + 31) & ~31;           // 512
  const int Cp = (C + 31) & ~31;           // 32
  const int dims[8][2] = { {F,H},{H,H},{H,H},{H,C},{C,H},{H,H},{H,H},{H,F} };

  // ---- workspace layout (256B aligned)
  char* ws = (char*)d_ws;
  size_t off = 0;
  auto alloc = [&](size_t bytes) {
    void* p = ws + off;
    off += (bytes + 255) & ~(size_t)255;
    return p;
  };
  int*   deg       = (int*)alloc((size_t)N * 4);
  int*   row_start = (int*)alloc((size_t)(N + 1) * 4);
  int*   cursor    = (int*)alloc((size_t)N * 4);
  float* dinv      = (float*)alloc((size_t)N * 4);
  int*   csr_src   = (int*)alloc((size_t)E * 4);
  float* csr_norm  = (float*)alloc((size_t)E * 4);
  unsigned short* xb = (unsigned short*)alloc((size_t)N * Fp * 2);
  WtPack wp;
  for (int i = 0; i < 8; ++i) {
    wp.W[i] = Wp[i];
    wp.K[i] = dims[i][0];
    wp.Nd[i] = dims[i][1];
    wp.Kp[i] = (dims[i][0] + 31) & ~31;
    wp.Ndp[i] = (dims[i][1] + 127) & ~127;
    wp.Wt[i] = (unsigned short*)alloc((size_t)wp.Ndp[i] * wp.Kp[i] * 2);
  }
  unsigned short* hb   = (unsigned short*)alloc((size_t)N * H * 2);
  unsigned short* actP = (unsigned short*)alloc((size_t)N * H * 2);
  unsigned short* actQ = (unsigned short*)alloc((size_t)N * H * 2);
  unsigned short* zpre = (unsigned short*)alloc((size_t)N * C * 2);
  unsigned short* zenb = (unsigned short*)alloc((size_t)N * C * 2);
  unsigned short* zagg = (unsigned short*)alloc((size_t)N * Cp * 2);
  (void)ws_size;

  // ---- d_out: x_de[N,F] | enc_h1[N,H] | enc_h2[N,H] | enc_h3[N,H] | z_en[N,C]
  float* out_f  = (float*)d_out;
  float* o_xde  = out_f;
  float* o_enc1 = out_f + (size_t)N * F;
  float* o_enc2 = o_enc1 + (size_t)N * H;
  float* o_enc3 = o_enc2 + (size_t)N * H;
  float* o_zen  = o_enc3 + (size_t)N * H;

  const int T = 256;
  // ---- graph preprocessing
  k_zero_int<<<(N + T - 1) / T, T, 0, stream>>>(deg, N);
  k_deg<<<(E + T - 1) / T, T, 0, stream>>>(dst, deg, E);
  k_scan_all<<<1, 1024, 0, stream>>>(deg, row_start, cursor, dinv, N);
  k_fill_csr<<<(E + T - 1) / T, T, 0, stream>>>(src, dst, dinv, cursor,
                                                csr_src, csr_norm, E);
  // ---- conversions
  {
    int nth = N * (Fp >> 3);
    k_cvt_pad<<<(nth + T - 1) / T, T, 0, stream>>>(x, xb, N, F, Fp);
    int maxElems = 0;
    for (int i = 0; i < 8; ++i) {
      int e = wp.Kp[i] * wp.Ndp[i];
      if (e > maxElems) maxElems = e;
    }
    dim3 g((maxElems + T - 1) / T, 8);
    k_wt_all<<<g, T, 0, stream>>>(wp);
  }

  auto gemm = [&](const unsigned short* A, int lda, int widx, const float* bias,
                  float* Cf, int ldcf, unsigned short* Cb, int ldcb,
                  int Nd, int relu) {
    dim3 grid((N + 127) / 128, (Nd + 127) / 128);
    gemm_bf16<<<grid, 256, 0, stream>>>(A, wp.Wt[widx], bias, Cf, ldcf, Cb, ldcb,
                                        N, wp.Kp[widx], Nd, lda, relu);
  };
  auto agg256 = [&](const unsigned short* h, const float* bias, float* Of,
                    unsigned short* Ob, int relu) {
    agg_wave<<<(N + 3) / 4, 256, 0, stream>>>(h, row_start, csr_src, csr_norm,
                                              dinv, bias, Of, Ob, N, relu);
  };

  // enc1: h = xb @ W0 ; enc_h1 = relu(agg(h)+b0)
  gemm(xb, Fp, 0, nullptr, nullptr, 0, hb, H, H, 0);
  agg256(hb, bp[0], o_enc1, actP, 1);
  // enc2
  gemm(actP, H, 1, nullptr, nullptr, 0, hb, H, H, 0);
  agg256(hb, bp[1], o_enc2, actQ, 1);
  // enc3
  gemm(actQ, H, 2, nullptr, nullptr, 0, hb, H, H, 0);
  agg256(hb, bp[2], o_enc3, actP, 1);
  // zen: zpre = enc_h3 @ W3 ; z_en = agg(zpre) + b3
  gemm(actP, H, 3, nullptr, nullptr, 0, zpre, C, C, 0);
  agg_small_t<10><<<(N + T - 1) / T, T, 0, stream>>>(
      zpre, C, row_start, csr_src, csr_norm, dinv, bp[3], o_zen, zenb, C, N);
  // dec1 (linearity): zagg = agg_nobias(z_en) ; d1 = relu(zagg @ W4 + b4)
  agg_small_t<10><<<(N + T - 1) / T, T, 0, stream>>>(
      zenb, C, row_start, csr_src, csr_norm, dinv, nullptr, nullptr, zagg, Cp, N);
  gemm(zagg, Cp, 4, bp[4], nullptr, 0, actQ, H, H, 1);
  // dec2
  gemm(actQ, H, 5, nullptr, nullptr, 0, hb, H, H, 0);
  agg256(hb, bp[5], nullptr, actP, 1);
  // dec3
  gemm(actP, H, 6, nullptr, nullptr, 0, hb, H, H, 0);
  agg256(hb, bp[6], nullptr, actQ, 1);
  // xde (linearity): dagg = agg_nobias(d3) ; x_de = dagg @ W7 + b7 (fp32)
  agg256(actQ, nullptr, nullptr, actP, 0);
  gemm(actP, H, 7, bp[7], o_xde, F, nullptr, 0, F, 0);
}

// Round 4
// 951.431 us; speedup vs baseline: 2.7866x; 1.0092x over previous
//
#include <hip/hip_runtime.h>

// GCN autoencoder on MI355X (gfx950).
// bf16-MFMA GEMM (global_load_lds + counted vmcnt pipeline) + 16B-lane gather agg.
// N=50000, E=800000, F=500, H=256, C=10 (derived at runtime).

typedef __attribute__((ext_vector_type(8))) short short8;           // 8 bf16
typedef __attribute__((ext_vector_type(4))) float f32x4;            // MFMA acc
typedef __attribute__((ext_vector_type(4))) unsigned short u16x4;   // 4 bf16

// ---------------------------------------------------------------- helpers

__device__ __forceinline__ float b2f(unsigned short u) {
  union { unsigned int i; float f; } v; v.i = ((unsigned int)u) << 16; return v.f;
}
__device__ __forceinline__ unsigned short f2b(float f) {  // RNE
  union { float f; unsigned int i; } v; v.f = f;
  unsigned int r = v.i + 0x7FFFu + ((v.i >> 16) & 1u);
  return (unsigned short)(r >> 16);
}
// unpack 2 bf16 from a uint
__device__ __forceinline__ void up2(unsigned int u, float& a, float& b) {
  union { unsigned int i; float f; } x, y;
  x.i = u << 16; y.i = u & 0xffff0000u;
  a = x.f; b = y.f;
}

// async global->LDS, 16B per lane; dest = lds_base(wave-uniform) + lane*16
__device__ __forceinline__ void gload16(const void* g, void* l) {
  __builtin_amdgcn_global_load_lds(
      (const __attribute__((address_space(1))) unsigned int*)g,
      (__attribute__((address_space(3))) unsigned int*)l, 16, 0, 0);
}

// ---------------------------------------------------------------- preproc

__global__ void k_zero_int(int* __restrict__ p, int n) {
  int i = blockIdx.x * blockDim.x + threadIdx.x;
  if (i < n) p[i] = 0;
}

__global__ void k_deg(const int* __restrict__ dst, int* __restrict__ deg, int E) {
  int i = blockIdx.x * blockDim.x + threadIdx.x;
  if (i < E) atomicAdd(&deg[dst[i]], 1);
}

// single-block: exclusive scan -> row_start & cursor; also dinv = rsqrt(deg+1)
__global__ __launch_bounds__(1024) void k_scan_all(const int* __restrict__ deg,
                                                   int* __restrict__ row_start,
                                                   int* __restrict__ cursor,
                                                   float* __restrict__ dinv, int n) {
  __shared__ int sh[1024];
  int t = threadIdx.x;
  int chunk = (n + 1023) / 1024;
  int lo = t * chunk;
  int hi = lo + chunk; if (hi > n) hi = n;
  int sum = 0;
  for (int i = lo; i < hi; ++i) sum += deg[i];
  sh[t] = sum;
  __syncthreads();
  for (int off = 1; off < 1024; off <<= 1) {
    int v = (t >= off) ? sh[t - off] : 0;
    __syncthreads();
    sh[t] += v;
    __syncthreads();
  }
  int run = sh[t] - sum;
  for (int i = lo; i < hi; ++i) {
    row_start[i] = run;
    cursor[i] = run;
    dinv[i] = rsqrtf((float)deg[i] + 1.0f);
    run += deg[i];
  }
  if (t == 1023) row_start[n] = sh[1023];
}

__global__ void k_fill_csr(const int* __restrict__ src, const int* __restrict__ dst,
                           const float* __restrict__ dinv, int* __restrict__ cursor,
                           int* __restrict__ csr_src, float* __restrict__ csr_norm, int E) {
  int e = blockIdx.x * blockDim.x + threadIdx.x;
  if (e < E) {
    int d = dst[e];
    int s = src[e];
    int pos = atomicAdd(&cursor[d], 1);
    csr_src[pos] = s;
    csr_norm[pos] = dinv[s] * dinv[d];
  }
}

// x[N][F] fp32 -> xb[N][Fp] bf16, zero-padded cols
__global__ void k_cvt_pad(const float* __restrict__ in, unsigned short* __restrict__ out,
                          int N, int F, int Fp) {
  int idx = blockIdx.x * blockDim.x + threadIdx.x;  // one per 8 outputs
  int perRow = Fp >> 3;
  int row = idx / perRow;
  int c = (idx - row * perRow) << 3;
  if (row >= N) return;
  unsigned short o[8];
  if (c + 8 <= F) {
    const float* p = in + (size_t)row * F + c;
    #pragma unroll
    for (int e = 0; e < 8; ++e) o[e] = f2b(p[e]);
  } else {
    #pragma unroll
    for (int e = 0; e < 8; ++e) {
      int cc = c + e;
      o[e] = (cc < F) ? f2b(in[(size_t)row * F + cc]) : (unsigned short)0;
    }
  }
  *(short8*)(out + (size_t)row * Fp + c) = *(short8*)o;
}

// all 8 weights: W[K][Nd] fp32 -> Wt[Ndp][Kp] bf16 (transposed, zero-padded)
struct WtPack {
  const float* W[8];
  unsigned short* Wt[8];
  int K[8], Nd[8], Kp[8], Ndp[8];
};

__global__ void k_wt_all(WtPack p) {
  int l = blockIdx.y;
  int idx = blockIdx.x * blockDim.x + threadIdx.x;
  int Kp = p.Kp[l], Ndp = p.Ndp[l];
  if (idx >= Kp * Ndp) return;
  int n = idx / Kp, k = idx - n * Kp;
  unsigned short v = 0;
  if (n < p.Nd[l] && k < p.K[l]) v = f2b(p.W[l][(size_t)k * p.Nd[l] + n]);
  p.Wt[l][idx] = v;
}

// ---------------------------------------------------------------- GEMM
// C[M,Nd] = A[M,Kp] @ Bt^T, A bf16 [M][lda] (K zero-padded), Bt bf16 [Ndp][Kp]
// (Ndp%128==0, Kp%32==0). 128x128 tile, 4 waves (2x2), 4x4 frags of
// mfma_f32_16x16x32_bf16. global_load_lds staging, double-buffered with
// COUNTED vmcnt (loads stay in flight across raw s_barrier).
// Slot-swizzle (slot ^= (row>>1)&3) applied at global source AND ds_read.

__global__ __launch_bounds__(256) void gemm_bf16(
    const unsigned short* __restrict__ A,
    const unsigned short* __restrict__ Bt,
    const float* __restrict__ bias,     // nullable, [Nd]
    float* __restrict__ Cf, int ldcf,   // nullable
    unsigned short* __restrict__ Cb, int ldcb,  // nullable
    int M, int Kp, int Nd, int lda, int relu) {
  __shared__ unsigned short As[2][4096];  // 128 rows x 32 bf16 (64B rows)
  __shared__ unsigned short Bs[2][4096];

  const int bm = blockIdx.x * 128;
  const int bn = blockIdx.y * 128;
  const int tid = threadIdx.x;
  const int wid = tid >> 6;
  const int lane = tid & 63;

  // staging source addresses (2 chunks of 1024B per wave per tile per matrix)
  const unsigned short* srcA[2];
  const unsigned short* srcB[2];
  #pragma unroll
  for (int j = 0; j < 2; ++j) {
    int chunk = wid * 2 + j;
    int r_st = chunk * 16 + (lane >> 2);    // tile row this lane fills
    int slot = lane & 3;                    // 16B slot within 64B row
    int sw = slot ^ ((r_st >> 1) & 3);      // swizzled source slot
    int gm = bm + r_st; if (gm > M - 1) gm = M - 1;   // clamp: dup rows unused
    srcA[j] = A + (size_t)gm * lda + sw * 8;
    int gn = bn + r_st;                     // always < Ndp (padded)
    srcB[j] = Bt + (size_t)gn * Kp + sw * 8;
  }

  // fragment read offsets (elements), swizzle matches staging
  const int wr = wid >> 1, wc = wid & 1;
  const int lrow = lane & 15;
  const int kgrp = lane >> 4;
  const int rA = wr * 64 + lrow;
  const int rB = wc * 64 + lrow;
  const int aoff = rA * 32 + (kgrp ^ ((rA >> 1) & 3)) * 8;
  const int boff = rB * 32 + (kgrp ^ ((rB >> 1) & 3)) * 8;

  f32x4 acc[4][4];
  #pragma unroll
  for (int i = 0; i < 4; ++i)
    #pragma unroll
    for (int j = 0; j < 4; ++j) acc[i][j] = (f32x4){0.f, 0.f, 0.f, 0.f};

  auto stage = [&](int buf, int k0) {
    #pragma unroll
    for (int j = 0; j < 2; ++j) {
      int chunk = wid * 2 + j;
      gload16(srcA[j] + k0, &As[buf][chunk * 512]);
      gload16(srcB[j] + k0, &Bs[buf][chunk * 512]);
    }
  };

  const int nt = Kp >> 5;
  stage(0, 0);
  if (nt > 1) stage(1, 32);
  int cur = 0;
  for (int t = 0; t < nt; ++t) {
    // wait: tile t landed (leave next tile's 4 DMAs in flight), then sync
    if (t + 1 < nt) asm volatile("s_waitcnt vmcnt(4)\n\ts_barrier" ::: "memory");
    else            asm volatile("s_waitcnt vmcnt(0)\n\ts_barrier" ::: "memory");

    const unsigned short* pA = &As[cur][aoff];
    const unsigned short* pB = &Bs[cur][boff];
    short8 a[4], b[4];
    #pragma unroll
    for (int mi = 0; mi < 4; ++mi) a[mi] = *(const short8*)(pA + mi * 512);
    #pragma unroll
    for (int nj = 0; nj < 4; ++nj) b[nj] = *(const short8*)(pB + nj * 512);

    // all reads done before anyone overwrites this buffer
    asm volatile("s_waitcnt lgkmcnt(0)\n\ts_barrier" ::: "memory");
    __builtin_amdgcn_sched_barrier(0);

    if (t + 2 < nt) stage(cur, (t + 2) * 32);   // overwrite just-read buffer

    #pragma unroll
    for (int mi = 0; mi < 4; ++mi)
      #pragma unroll
      for (int nj = 0; nj < 4; ++nj)
        acc[mi][nj] = __builtin_amdgcn_mfma_f32_16x16x32_bf16(a[mi], b[nj], acc[mi][nj], 0, 0, 0);
    cur ^= 1;
  }

  // epilogue: frag D row = 4*kgrp + rr, col = lrow
  const int orow = bm + wr * 64;
  const int ocol = bn + wc * 64;
  float bv[4];
  #pragma unroll
  for (int nj = 0; nj < 4; ++nj) {
    int gn = ocol + nj * 16 + lrow;
    bv[nj] = (bias && gn < Nd) ? bias[gn] : 0.f;
  }
  #pragma unroll
  for (int mi = 0; mi < 4; ++mi) {
    #pragma unroll
    for (int rr = 0; rr < 4; ++rr) {
      int gm = orow + mi * 16 + 4 * kgrp + rr;
      if (gm >= M) continue;
      #pragma unroll
      for (int nj = 0; nj < 4; ++nj) {
        int gn = ocol + nj * 16 + lrow;
        if (gn >= Nd) continue;
        float v = acc[mi][nj][rr] + bv[nj];
        if (relu) v = fmaxf(v, 0.f);
        if (Cf) Cf[(size_t)gm * ldcf + gn] = v;
        if (Cb) Cb[(size_t)gm * ldcb + gn] = f2b(v);
      }
    }
  }
}

// ---------------------------------------------------------------- aggregation
// Wave per node; wave split into two 32-lane halves, each gathers a different
// edge at 16B/lane (short8, dwordx4). Lane hl covers feats hl*8..hl*8+7.
// half0 init: self term; half1 init: bias. Cross-half combine via shfl_xor(32).
// half0 stores bf16 mirror; half1 stores fp32 d_out row.

__global__ __launch_bounds__(256) void agg_wave(
    const unsigned short* __restrict__ h,
    const int* __restrict__ row_start, const int* __restrict__ csr_src,
    const float* __restrict__ csr_norm, const float* __restrict__ dinv,
    const float* __restrict__ bias,      // nullable
    float* __restrict__ Of,              // nullable
    unsigned short* __restrict__ Ob,     // non-null in all call sites
    int N, int relu) {
  const int w = threadIdx.x >> 6;
  const int lane = threadIdx.x & 63;
  const int i = blockIdx.x * 4 + w;
  if (i >= N) return;
  const int half = lane >> 5;
  const int hl = lane & 31;
  const int f0 = hl * 8;

  float acc[8];
  if (half == 0) {
    float sn = dinv[i]; sn *= sn;
    short8 hv = *(const short8*)(h + ((size_t)i << 8) + f0);
    #pragma unroll
    for (int j = 0; j < 8; ++j) acc[j] = b2f(((const unsigned short*)&hv)[j]) * sn;
  } else if (bias) {
    #pragma unroll
    for (int j = 0; j < 8; ++j) acc[j] = bias[f0 + j];
  } else {
    #pragma unroll
    for (int j = 0; j < 8; ++j) acc[j] = 0.f;
  }

  int s = row_start[i];
  const int s1 = row_start[i + 1];
  // main: 4 edges per trip (2 per half)
  for (; s + 4 <= s1; s += 4) {
    int e0 = s + half, e1 = s + 2 + half;
    int i0 = csr_src[e0], i1 = csr_src[e1];
    float w0 = csr_norm[e0], w1 = csr_norm[e1];
    short8 v0 = *(const short8*)(h + ((size_t)i0 << 8) + f0);
    short8 v1 = *(const short8*)(h + ((size_t)i1 << 8) + f0);
    #pragma unroll
    for (int j = 0; j < 8; ++j)
      acc[j] = fmaf(b2f(((const unsigned short*)&v0)[j]), w0, acc[j]);
    #pragma unroll
    for (int j = 0; j < 8; ++j)
      acc[j] = fmaf(b2f(((const unsigned short*)&v1)[j]), w1, acc[j]);
  }
  // tail: predicated pairs
  for (; s < s1; s += 2) {
    int e = s + half;
    bool valid = e < s1;
    int idx = valid ? csr_src[e] : 0;
    float wt = valid ? csr_norm[e] : 0.f;
    short8 vv = *(const short8*)(h + ((size_t)idx << 8) + f0);
    #pragma unroll
    for (int j = 0; j < 8; ++j)
      acc[j] = fmaf(b2f(((const unsigned short*)&vv)[j]), wt, acc[j]);
  }

  // combine halves (both halves end with the full sum)
  #pragma unroll
  for (int j = 0; j < 8; ++j) acc[j] += __shfl_xor(acc[j], 32, 64);
  if (relu) {
    #pragma unroll
    for (int j = 0; j < 8; ++j) acc[j] = fmaxf(acc[j], 0.f);
  }

  size_t o = ((size_t)i << 8) + f0;
  if (half == 0) {
    if (Ob) {
      unsigned short ob[8];
      #pragma unroll
      for (int j = 0; j < 8; ++j) ob[j] = f2b(acc[j]);
      *(short8*)(Ob + o) = *(short8*)ob;
    }
  } else if (Of) {
    f32x4 lo = {acc[0], acc[1], acc[2], acc[3]};
    f32x4 hi = {acc[4], acc[5], acc[6], acc[7]};
    *(f32x4*)(Of + o) = lo;
    *(f32x4*)(Of + o + 4) = hi;
  }
}

// Code-path aggregation (CD=10), rows stored with ld=12 (24B, 8B-aligned).
template <int CD>
__global__ void agg_code(
    const unsigned short* __restrict__ h,    // ld 12
    const int* __restrict__ row_start, const int* __restrict__ csr_src,
    const float* __restrict__ csr_norm, const float* __restrict__ dinv,
    const float* __restrict__ bias,          // nullable
    float* __restrict__ Of,                  // nullable, ld CD
    unsigned short* __restrict__ Ob,         // nullable, ld ldo (zero-padded)
    int ldo, int N) {
  const int i = blockIdx.x * blockDim.x + threadIdx.x;
  if (i >= N) return;
  float acc[CD];
  float sn = dinv[i]; sn *= sn;
  {
    const unsigned short* hi = h + (size_t)i * 12;
    uint2 d0 = *(const uint2*)hi;
    uint2 d1 = *(const uint2*)(hi + 4);
    unsigned int d2 = *(const unsigned int*)(hi + 8);
    float t[10];
    up2(d0.x, t[0], t[1]); up2(d0.y, t[2], t[3]);
    up2(d1.x, t[4], t[5]); up2(d1.y, t[6], t[7]);
    up2(d2,   t[8], t[9]);
    #pragma unroll
    for (int f = 0; f < CD; ++f) acc[f] = t[f] * sn + (bias ? bias[f] : 0.f);
  }
  const int s1 = row_start[i + 1];
  for (int s = row_start[i]; s < s1; ++s) {
    const unsigned short* hs = h + (size_t)csr_src[s] * 12;
    float wgt = csr_norm[s];
    uint2 d0 = *(const uint2*)hs;
    uint2 d1 = *(const uint2*)(hs + 4);
    unsigned int d2 = *(const unsigned int*)(hs + 8);
    float t[10];
    up2(d0.x, t[0], t[1]); up2(d0.y, t[2], t[3]);
    up2(d1.x, t[4], t[5]); up2(d1.y, t[6], t[7]);
    up2(d2,   t[8], t[9]);
    #pragma unroll
    for (int f = 0; f < CD; ++f) acc[f] = fmaf(t[f], wgt, acc[f]);
  }
  if (Of) {
    #pragma unroll
    for (int f = 0; f < CD; ++f) Of[(size_t)i * CD + f] = acc[f];
  }
  if (Ob) {
    #pragma unroll
    for (int f = 0; f < CD; ++f) Ob[(size_t)i * ldo + f] = f2b(acc[f]);
    for (int f = CD; f < ldo; ++f) Ob[(size_t)i * ldo + f] = 0;
  }
}

// ---------------------------------------------------------------- driver

extern "C" void kernel_launch(void* const* d_in, const int* in_sizes, int n_in,
                              void* d_out, int out_size, void* d_ws, size_t ws_size,
                              hipStream_t stream) {
  const float* x   = (const float*)d_in[0];
  const int*   src = (const int*)d_in[1];
  const int*   dst = (const int*)d_in[2];
  const float* Wp[8];
  const float* bp[8];
  for (int i = 0; i < 8; ++i) {
    Wp[i] = (const float*)d_in[3 + 2 * i];
    bp[i] = (const float*)d_in[4 + 2 * i];
  }

  const int H = in_sizes[4];
  const int F = in_sizes[3] / H;
  const int N = in_sizes[0] / F;
  const int E = in_sizes[1];
  const int C = in_sizes[10];   // = 10

  const int Fp = (F + 31) & ~31;           // 512
  const int Cp = (C + 31) & ~31;           // 32
  const int dims[8][2] = { {F,H},{H,H},{H,H},{H,C},{C,H},{H,H},{H,H},{H,F} };

  // ---- workspace layout (256B aligned)
  char* ws = (char*)d_ws;
  size_t off = 0;
  auto alloc = [&](size_t bytes) {
    void* p = ws + off;
    off += (bytes + 255) & ~(size_t)255;
    return p;
  };
  int*   deg       = (int*)alloc((size_t)N * 4);
  int*   row_start = (int*)alloc((size_t)(N + 1) * 4);
  int*   cursor    = (int*)alloc((size_t)N * 4);
  float* dinv      = (float*)alloc((size_t)N * 4);
  int*   csr_src   = (int*)alloc((size_t)E * 4);
  float* csr_norm  = (float*)alloc((size_t)E * 4);
  unsigned short* xb = (unsigned short*)alloc((size_t)N * Fp * 2);
  WtPack wp;
  for (int i = 0; i < 8; ++i) {
    wp.W[i] = Wp[i];
    wp.K[i] = dims[i][0];
    wp.Nd[i] = dims[i][1];
    wp.Kp[i] = (dims[i][0] + 31) & ~31;
    wp.Ndp[i] = (dims[i][1] + 127) & ~127;
    wp.Wt[i] = (unsigned short*)alloc((size_t)wp.Ndp[i] * wp.Kp[i] * 2);
  }
  unsigned short* hb   = (unsigned short*)alloc((size_t)N * H * 2);
  unsigned short* actP = (unsigned short*)alloc((size_t)N * H * 2);
  unsigned short* actQ = (unsigned short*)alloc((size_t)N * H * 2);
  unsigned short* zpre = (unsigned short*)alloc((size_t)N * 12 * 2);
  unsigned short* zenb = (unsigned short*)alloc((size_t)N * 12 * 2);
  unsigned short* zagg = (unsigned short*)alloc((size_t)N * Cp * 2);
  (void)ws_size;

  // ---- d_out: x_de[N,F] | enc_h1[N,H] | enc_h2[N,H] | enc_h3[N,H] | z_en[N,C]
  float* out_f  = (float*)d_out;
  float* o_xde  = out_f;
  float* o_enc1 = out_f + (size_t)N * F;
  float* o_enc2 = o_enc1 + (size_t)N * H;
  float* o_enc3 = o_enc2 + (size_t)N * H;
  float* o_zen  = o_enc3 + (size_t)N * H;

  const int T = 256;
  // ---- graph preprocessing
  k_zero_int<<<(N + T - 1) / T, T, 0, stream>>>(deg, N);
  k_deg<<<(E + T - 1) / T, T, 0, stream>>>(dst, deg, E);
  k_scan_all<<<1, 1024, 0, stream>>>(deg, row_start, cursor, dinv, N);
  k_fill_csr<<<(E + T - 1) / T, T, 0, stream>>>(src, dst, dinv, cursor,
                                                csr_src, csr_norm, E);
  // ---- conversions
  {
    int nth = N * (Fp >> 3);
    k_cvt_pad<<<(nth + T - 1) / T, T, 0, stream>>>(x, xb, N, F, Fp);
    int maxElems = 0;
    for (int i = 0; i < 8; ++i) {
      int e = wp.Kp[i] * wp.Ndp[i];
      if (e > maxElems) maxElems = e;
    }
    dim3 g((maxElems + T - 1) / T, 8);
    k_wt_all<<<g, T, 0, stream>>>(wp);
  }

  auto gemm = [&](const unsigned short* A, int lda, int widx, const float* bias,
                  float* Cf, int ldcf, unsigned short* Cb, int ldcb,
                  int Nd, int relu) {
    dim3 grid((N + 127) / 128, (Nd + 127) / 128);
    gemm_bf16<<<grid, 256, 0, stream>>>(A, wp.Wt[widx], bias, Cf, ldcf, Cb, ldcb,
                                        N, wp.Kp[widx], Nd, lda, relu);
  };
  auto agg256 = [&](const unsigned short* h, const float* bias, float* Of,
                    unsigned short* Ob, int relu) {
    agg_wave<<<(N + 3) / 4, 256, 0, stream>>>(h, row_start, csr_src, csr_norm,
                                              dinv, bias, Of, Ob, N, relu);
  };

  // enc1: h = xb @ W0 ; enc_h1 = relu(agg(h)+b0)
  gemm(xb, Fp, 0, nullptr, nullptr, 0, hb, H, H, 0);
  agg256(hb, bp[0], o_enc1, actP, 1);
  // enc2
  gemm(actP, H, 1, nullptr, nullptr, 0, hb, H, H, 0);
  agg256(hb, bp[1], o_enc2, actQ, 1);
  // enc3
  gemm(actQ, H, 2, nullptr, nullptr, 0, hb, H, H, 0);
  agg256(hb, bp[2], o_enc3, actP, 1);
  // zen: zpre = enc_h3 @ W3 (ld 12) ; z_en = agg(zpre) + b3
  gemm(actP, H, 3, nullptr, nullptr, 0, zpre, 12, C, 0);
  agg_code<10><<<(N + T - 1) / T, T, 0, stream>>>(
      zpre, row_start, csr_src, csr_norm, dinv, bp[3], o_zen, zenb, 12, N);
  // dec1 (linearity): zagg = agg_nobias(z_en) ; d1 = relu(zagg @ W4 + b4)
  agg_code<10><<<(N + T - 1) / T, T, 0, stream>>>(
      zenb, row_start, csr_src, csr_norm, dinv, nullptr, nullptr, zagg, Cp, N);
  gemm(zagg, Cp, 4, bp[4], nullptr, 0, actQ, H, H, 1);
  // dec2
  gemm(actQ, H, 5, nullptr, nullptr, 0, hb, H, H, 0);
  agg256(hb, bp[5], nullptr, actP, 1);
  // dec3
  gemm(actP, H, 6, nullptr, nullptr, 0, hb, H, H, 0);
  agg256(hb, bp[6], nullptr, actQ, 1);
  // xde (linearity): dagg = agg_nobias(d3) ; x_de = dagg @ W7 + b7 (fp32)
  agg256(actQ, nullptr, nullptr, actP, 0);
  gemm(actP, H, 7, bp[7], o_xde, F, nullptr, 0, F, 0);
}

// Round 5
// 881.749 us; speedup vs baseline: 3.0068x; 1.0790x over previous
//
#include <hip/hip_runtime.h>

// GCN autoencoder on MI355X (gfx950).
// bf16-MFMA GEMM (global_load_lds + counted vmcnt) + deep-unrolled gather agg.
// N=50000, E=800000, F=500, H=256, C=10 (derived at runtime).

typedef __attribute__((ext_vector_type(8))) short short8;           // 8 bf16
typedef __attribute__((ext_vector_type(4))) float f32x4;            // MFMA acc

// ---------------------------------------------------------------- helpers

__device__ __forceinline__ float b2f(unsigned short u) {
  union { unsigned int i; float f; } v; v.i = ((unsigned int)u) << 16; return v.f;
}
__device__ __forceinline__ unsigned short f2b(float f) {  // RNE
  union { float f; unsigned int i; } v; v.f = f;
  unsigned int r = v.i + 0x7FFFu + ((v.i >> 16) & 1u);
  return (unsigned short)(r >> 16);
}
__device__ __forceinline__ void up2(unsigned int u, float& a, float& b) {
  union { unsigned int i; float f; } x, y;
  x.i = u << 16; y.i = u & 0xffff0000u;
  a = x.f; b = y.f;
}
__device__ __forceinline__ float i2f(int i) {
  union { int i; float f; } v; v.i = i; return v.f;
}

// async global->LDS, 16B per lane; dest = lds_base(wave-uniform) + lane*16
__device__ __forceinline__ void gload16(const void* g, void* l) {
  __builtin_amdgcn_global_load_lds(
      (const __attribute__((address_space(1))) unsigned int*)g,
      (__attribute__((address_space(3))) unsigned int*)l, 16, 0, 0);
}

// ---------------------------------------------------------------- preproc

__global__ void k_zero_int(int* __restrict__ p, int n) {
  int i = blockIdx.x * blockDim.x + threadIdx.x;
  if (i < n) p[i] = 0;
}

__global__ void k_deg(const int* __restrict__ dst, int* __restrict__ deg, int E) {
  int i = blockIdx.x * blockDim.x + threadIdx.x;
  if (i < E) atomicAdd(&deg[dst[i]], 1);
}

// 3-pass parallel scan (n up to 256*1024)
__global__ void k_scan1(const int* __restrict__ deg, int* __restrict__ part, int n) {
  __shared__ int sh[256];
  int i = blockIdx.x * 256 + threadIdx.x;
  sh[threadIdx.x] = (i < n) ? deg[i] : 0;
  __syncthreads();
  for (int o = 128; o > 0; o >>= 1) {
    if (threadIdx.x < o) sh[threadIdx.x] += sh[threadIdx.x + o];
    __syncthreads();
  }
  if (threadIdx.x == 0) part[blockIdx.x] = sh[0];
}

__global__ __launch_bounds__(1024) void k_scan2(int* __restrict__ part, int nb) {
  __shared__ int sh[1024];
  int t = threadIdx.x;
  int v = (t < nb) ? part[t] : 0;
  sh[t] = v;
  __syncthreads();
  for (int off = 1; off < 1024; off <<= 1) {
    int u = (t >= off) ? sh[t - off] : 0;
    __syncthreads();
    sh[t] += u;
    __syncthreads();
  }
  if (t < nb) part[t] = sh[t] - v;  // exclusive
}

__global__ void k_scan3(const int* __restrict__ deg, const int* __restrict__ part,
                        int* __restrict__ row_start, int* __restrict__ cursor,
                        float* __restrict__ dinv, int n) {
  __shared__ int sh[256];
  int t = threadIdx.x;
  int i = blockIdx.x * 256 + t;
  int v = (i < n) ? deg[i] : 0;
  sh[t] = v;
  __syncthreads();
  for (int off = 1; off < 256; off <<= 1) {
    int u = (t >= off) ? sh[t - off] : 0;
    __syncthreads();
    sh[t] += u;
    __syncthreads();
  }
  if (i < n) {
    int excl = part[blockIdx.x] + sh[t] - v;
    row_start[i] = excl;
    cursor[i] = excl;
    dinv[i] = rsqrtf((float)v + 1.0f);
    if (i == n - 1) row_start[n] = excl + v;
  }
}

// fused CSR entries: .x = src index, .y = float bits of norm
__global__ void k_fill_csr(const int* __restrict__ src, const int* __restrict__ dst,
                           const float* __restrict__ dinv, int* __restrict__ cursor,
                           int2* __restrict__ csr_ent, int E) {
  int e = blockIdx.x * blockDim.x + threadIdx.x;
  if (e < E) {
    int d = dst[e];
    int s = src[e];
    int pos = atomicAdd(&cursor[d], 1);
    float nrm = dinv[s] * dinv[d];
    csr_ent[pos] = make_int2(s, __float_as_int(nrm));
  }
}

// x[N][F] fp32 -> xb[N][Fp] bf16, zero-padded cols
__global__ void k_cvt_pad(const float* __restrict__ in, unsigned short* __restrict__ out,
                          int N, int F, int Fp) {
  int idx = blockIdx.x * blockDim.x + threadIdx.x;
  int perRow = Fp >> 3;
  int row = idx / perRow;
  int c = (idx - row * perRow) << 3;
  if (row >= N) return;
  unsigned short o[8];
  if (c + 8 <= F) {
    const float* p = in + (size_t)row * F + c;
    #pragma unroll
    for (int e = 0; e < 8; ++e) o[e] = f2b(p[e]);
  } else {
    #pragma unroll
    for (int e = 0; e < 8; ++e) {
      int cc = c + e;
      o[e] = (cc < F) ? f2b(in[(size_t)row * F + cc]) : (unsigned short)0;
    }
  }
  *(short8*)(out + (size_t)row * Fp + c) = *(short8*)o;
}

// all 8 weights: W[K][Nd] fp32 -> Wt[Ndp][Kp] bf16 (transposed, zero-padded)
struct WtPack {
  const float* W[8];
  unsigned short* Wt[8];
  int K[8], Nd[8], Kp[8], Ndp[8];
};

__global__ void k_wt_all(WtPack p) {
  int l = blockIdx.y;
  int idx = blockIdx.x * blockDim.x + threadIdx.x;
  int Kp = p.Kp[l], Ndp = p.Ndp[l];
  if (idx >= Kp * Ndp) return;
  int n = idx / Kp, k = idx - n * Kp;
  unsigned short v = 0;
  if (n < p.Nd[l] && k < p.K[l]) v = f2b(p.W[l][(size_t)k * p.Nd[l] + n]);
  p.Wt[l][idx] = v;
}

// ---------------------------------------------------------------- GEMM
// C[M,Nd] = A[M,Kp] @ Bt^T, A bf16 [M][lda], Bt bf16 [Ndp][Kp], padded.
// 128x128 tile, 4 waves (2x2), 4x4 frags of mfma_f32_16x16x32_bf16.
// global_load_lds staging, 2-deep, counted vmcnt across raw barriers.
// Slot-swizzle (slot ^= (row>>1)&3) at global source AND ds_read.

__global__ __launch_bounds__(256) void gemm_bf16(
    const unsigned short* __restrict__ A,
    const unsigned short* __restrict__ Bt,
    const float* __restrict__ bias,     // nullable, [Nd]
    float* __restrict__ Cf, int ldcf,   // nullable (NT-stored)
    unsigned short* __restrict__ Cb, int ldcb,  // nullable
    int M, int Kp, int Nd, int lda, int relu) {
  __shared__ unsigned short As[2][4096];  // 128 rows x 32 bf16 (64B rows)
  __shared__ unsigned short Bs[2][4096];

  const int bm = blockIdx.x * 128;
  const int bn = blockIdx.y * 128;
  const int tid = threadIdx.x;
  const int wid = tid >> 6;
  const int lane = tid & 63;

  const unsigned short* srcA[2];
  const unsigned short* srcB[2];
  #pragma unroll
  for (int j = 0; j < 2; ++j) {
    int chunk = wid * 2 + j;
    int r_st = chunk * 16 + (lane >> 2);
    int slot = lane & 3;
    int sw = slot ^ ((r_st >> 1) & 3);
    int gm = bm + r_st; if (gm > M - 1) gm = M - 1;   // clamp: dup rows unused
    srcA[j] = A + (size_t)gm * lda + sw * 8;
    int gn = bn + r_st;
    srcB[j] = Bt + (size_t)gn * Kp + sw * 8;
  }

  const int wr = wid >> 1, wc = wid & 1;
  const int lrow = lane & 15;
  const int kgrp = lane >> 4;
  const int rA = wr * 64 + lrow;
  const int rB = wc * 64 + lrow;
  const int aoff = rA * 32 + (kgrp ^ ((rA >> 1) & 3)) * 8;
  const int boff = rB * 32 + (kgrp ^ ((rB >> 1) & 3)) * 8;

  f32x4 acc[4][4];
  #pragma unroll
  for (int i = 0; i < 4; ++i)
    #pragma unroll
    for (int j = 0; j < 4; ++j) acc[i][j] = (f32x4){0.f, 0.f, 0.f, 0.f};

  auto stage = [&](int buf, int k0) {
    #pragma unroll
    for (int j = 0; j < 2; ++j) {
      int chunk = wid * 2 + j;
      gload16(srcA[j] + k0, &As[buf][chunk * 512]);
      gload16(srcB[j] + k0, &Bs[buf][chunk * 512]);
    }
  };

  const int nt = Kp >> 5;
  stage(0, 0);
  if (nt > 1) stage(1, 32);
  int cur = 0;
  for (int t = 0; t < nt; ++t) {
    if (t + 1 < nt) asm volatile("s_waitcnt vmcnt(4)\n\ts_barrier" ::: "memory");
    else            asm volatile("s_waitcnt vmcnt(0)\n\ts_barrier" ::: "memory");

    const unsigned short* pA = &As[cur][aoff];
    const unsigned short* pB = &Bs[cur][boff];
    short8 a[4], b[4];
    #pragma unroll
    for (int mi = 0; mi < 4; ++mi) a[mi] = *(const short8*)(pA + mi * 512);
    #pragma unroll
    for (int nj = 0; nj < 4; ++nj) b[nj] = *(const short8*)(pB + nj * 512);

    asm volatile("s_waitcnt lgkmcnt(0)\n\ts_barrier" ::: "memory");
    __builtin_amdgcn_sched_barrier(0);

    if (t + 2 < nt) stage(cur, (t + 2) * 32);

    #pragma unroll
    for (int mi = 0; mi < 4; ++mi)
      #pragma unroll
      for (int nj = 0; nj < 4; ++nj)
        acc[mi][nj] = __builtin_amdgcn_mfma_f32_16x16x32_bf16(a[mi], b[nj], acc[mi][nj], 0, 0, 0);
    cur ^= 1;
  }

  const int orow = bm + wr * 64;
  const int ocol = bn + wc * 64;
  float bv[4];
  #pragma unroll
  for (int nj = 0; nj < 4; ++nj) {
    int gn = ocol + nj * 16 + lrow;
    bv[nj] = (bias && gn < Nd) ? bias[gn] : 0.f;
  }
  #pragma unroll
  for (int mi = 0; mi < 4; ++mi) {
    #pragma unroll
    for (int rr = 0; rr < 4; ++rr) {
      int gm = orow + mi * 16 + 4 * kgrp + rr;
      if (gm >= M) continue;
      #pragma unroll
      for (int nj = 0; nj < 4; ++nj) {
        int gn = ocol + nj * 16 + lrow;
        if (gn >= Nd) continue;
        float v = acc[mi][nj][rr] + bv[nj];
        if (relu) v = fmaxf(v, 0.f);
        if (Cf) __builtin_nontemporal_store(v, &Cf[(size_t)gm * ldcf + gn]);
        if (Cb) Cb[(size_t)gm * ldcb + gn] = f2b(v);
      }
    }
  }
}

// ---------------------------------------------------------------- aggregation
// Wave per node; two 32-lane halves, each gathers its own edges at 16B/lane.
// 8 edges per main trip (4 per half) for deep MLP. Fused int2 CSR entries,
// NT-loaded (don't evict h from L2). Cross-half combine via shfl_xor(32).
// half0 stores bf16 mirror (cached); half1 stores fp32 d_out row (NT).

__global__ __launch_bounds__(256) void agg_wave(
    const unsigned short* __restrict__ h,
    const int* __restrict__ row_start, const int2* __restrict__ csr_ent,
    const float* __restrict__ dinv,
    const float* __restrict__ bias,      // nullable
    float* __restrict__ Of,              // nullable
    unsigned short* __restrict__ Ob,     // nullable
    int N, int relu) {
  const int w = threadIdx.x >> 6;
  const int lane = threadIdx.x & 63;
  const int i = blockIdx.x * 4 + w;
  if (i >= N) return;
  const int half = lane >> 5;
  const int hl = lane & 31;
  const int f0 = hl * 8;

  float acc[8];
  if (half == 0) {
    float sn = dinv[i]; sn *= sn;
    short8 hv = *(const short8*)(h + ((size_t)i << 8) + f0);
    #pragma unroll
    for (int j = 0; j < 8; ++j) acc[j] = b2f(((const unsigned short*)&hv)[j]) * sn;
  } else if (bias) {
    #pragma unroll
    for (int j = 0; j < 8; ++j) acc[j] = bias[f0 + j];
  } else {
    #pragma unroll
    for (int j = 0; j < 8; ++j) acc[j] = 0.f;
  }

  int s = row_start[i];
  const int s1 = row_start[i + 1];

  // main: 8 edges per trip (4 per half, interleaved)
  for (; s + 8 <= s1; s += 8) {
    long long p0 = __builtin_nontemporal_load((const long long*)(csr_ent + s + half));
    long long p1 = __builtin_nontemporal_load((const long long*)(csr_ent + s + 2 + half));
    long long p2 = __builtin_nontemporal_load((const long long*)(csr_ent + s + 4 + half));
    long long p3 = __builtin_nontemporal_load((const long long*)(csr_ent + s + 6 + half));
    short8 v0 = *(const short8*)(h + ((size_t)(int)p0 << 8) + f0);
    short8 v1 = *(const short8*)(h + ((size_t)(int)p1 << 8) + f0);
    short8 v2 = *(const short8*)(h + ((size_t)(int)p2 << 8) + f0);
    short8 v3 = *(const short8*)(h + ((size_t)(int)p3 << 8) + f0);
    float w0 = i2f((int)(p0 >> 32)), w1 = i2f((int)(p1 >> 32));
    float w2 = i2f((int)(p2 >> 32)), w3 = i2f((int)(p3 >> 32));
    #pragma unroll
    for (int j = 0; j < 8; ++j)
      acc[j] = fmaf(b2f(((const unsigned short*)&v0)[j]), w0, acc[j]);
    #pragma unroll
    for (int j = 0; j < 8; ++j)
      acc[j] = fmaf(b2f(((const unsigned short*)&v1)[j]), w1, acc[j]);
    #pragma unroll
    for (int j = 0; j < 8; ++j)
      acc[j] = fmaf(b2f(((const unsigned short*)&v2)[j]), w2, acc[j]);
    #pragma unroll
    for (int j = 0; j < 8; ++j)
      acc[j] = fmaf(b2f(((const unsigned short*)&v3)[j]), w3, acc[j]);
  }
  // 4 edges (2 per half)
  for (; s + 4 <= s1; s += 4) {
    long long p0 = __builtin_nontemporal_load((const long long*)(csr_ent + s + half));
    long long p1 = __builtin_nontemporal_load((const long long*)(csr_ent + s + 2 + half));
    short8 v0 = *(const short8*)(h + ((size_t)(int)p0 << 8) + f0);
    short8 v1 = *(const short8*)(h + ((size_t)(int)p1 << 8) + f0);
    float w0 = i2f((int)(p0 >> 32)), w1 = i2f((int)(p1 >> 32));
    #pragma unroll
    for (int j = 0; j < 8; ++j)
      acc[j] = fmaf(b2f(((const unsigned short*)&v0)[j]), w0, acc[j]);
    #pragma unroll
    for (int j = 0; j < 8; ++j)
      acc[j] = fmaf(b2f(((const unsigned short*)&v1)[j]), w1, acc[j]);
  }
  // predicated pairs
  for (; s < s1; s += 2) {
    int e = s + half;
    bool valid = e < s1;
    long long p0 = valid
        ? __builtin_nontemporal_load((const long long*)(csr_ent + e)) : 0ll;
    short8 vv = *(const short8*)(h + ((size_t)(int)p0 << 8) + f0);
    float wt = i2f((int)(p0 >> 32));
    #pragma unroll
    for (int j = 0; j < 8; ++j)
      acc[j] = fmaf(b2f(((const unsigned short*)&vv)[j]), wt, acc[j]);
  }

  #pragma unroll
  for (int j = 0; j < 8; ++j) acc[j] += __shfl_xor(acc[j], 32, 64);
  if (relu) {
    #pragma unroll
    for (int j = 0; j < 8; ++j) acc[j] = fmaxf(acc[j], 0.f);
  }

  size_t o = ((size_t)i << 8) + f0;
  if (half == 0) {
    if (Ob) {
      unsigned short ob[8];
      #pragma unroll
      for (int j = 0; j < 8; ++j) ob[j] = f2b(acc[j]);
      *(short8*)(Ob + o) = *(short8*)ob;
    }
  } else if (Of) {
    f32x4 lo = {acc[0], acc[1], acc[2], acc[3]};
    f32x4 hi = {acc[4], acc[5], acc[6], acc[7]};
    __builtin_nontemporal_store(lo, (f32x4*)(Of + o));
    __builtin_nontemporal_store(hi, (f32x4*)(Of + o + 4));
  }
}

// Code-path aggregation (CD=10), rows stored with ld=12 (24B, 8B-aligned).
template <int CD>
__global__ void agg_code(
    const unsigned short* __restrict__ h,    // ld 12
    const int* __restrict__ row_start, const int2* __restrict__ csr_ent,
    const float* __restrict__ dinv,
    const float* __restrict__ bias,          // nullable
    float* __restrict__ Of,                  // nullable, ld CD (NT)
    unsigned short* __restrict__ Ob,         // nullable, ld ldo (zero-padded)
    int ldo, int N) {
  const int i = blockIdx.x * blockDim.x + threadIdx.x;
  if (i >= N) return;
  float acc[CD];
  float sn = dinv[i]; sn *= sn;
  {
    const unsigned short* hi = h + (size_t)i * 12;
    uint2 d0 = *(const uint2*)hi;
    uint2 d1 = *(const uint2*)(hi + 4);
    unsigned int d2 = *(const unsigned int*)(hi + 8);
    float t[10];
    up2(d0.x, t[0], t[1]); up2(d0.y, t[2], t[3]);
    up2(d1.x, t[4], t[5]); up2(d1.y, t[6], t[7]);
    up2(d2,   t[8], t[9]);
    #pragma unroll
    for (int f = 0; f < CD; ++f) acc[f] = t[f] * sn + (bias ? bias[f] : 0.f);
  }
  const int s1 = row_start[i + 1];
  for (int s = row_start[i]; s < s1; ++s) {
    long long p = __builtin_nontemporal_load((const long long*)(csr_ent + s));
    const unsigned short* hs = h + (size_t)(int)p * 12;
    float wgt = i2f((int)(p >> 32));
    uint2 d0 = *(const uint2*)hs;
    uint2 d1 = *(const uint2*)(hs + 4);
    unsigned int d2 = *(const unsigned int*)(hs + 8);
    float t[10];
    up2(d0.x, t[0], t[1]); up2(d0.y, t[2], t[3]);
    up2(d1.x, t[4], t[5]); up2(d1.y, t[6], t[7]);
    up2(d2,   t[8], t[9]);
    #pragma unroll
    for (int f = 0; f < CD; ++f) acc[f] = fmaf(t[f], wgt, acc[f]);
  }
  if (Of) {
    #pragma unroll
    for (int f = 0; f < CD; ++f)
      __builtin_nontemporal_store(acc[f], &Of[(size_t)i * CD + f]);
  }
  if (Ob) {
    #pragma unroll
    for (int f = 0; f < CD; ++f) Ob[(size_t)i * ldo + f] = f2b(acc[f]);
    for (int f = CD; f < ldo; ++f) Ob[(size_t)i * ldo + f] = 0;
  }
}

// ---------------------------------------------------------------- driver

extern "C" void kernel_launch(void* const* d_in, const int* in_sizes, int n_in,
                              void* d_out, int out_size, void* d_ws, size_t ws_size,
                              hipStream_t stream) {
  const float* x   = (const float*)d_in[0];
  const int*   src = (const int*)d_in[1];
  const int*   dst = (const int*)d_in[2];
  const float* Wp[8];
  const float* bp[8];
  for (int i = 0; i < 8; ++i) {
    Wp[i] = (const float*)d_in[3 + 2 * i];
    bp[i] = (const float*)d_in[4 + 2 * i];
  }

  const int H = in_sizes[4];
  const int F = in_sizes[3] / H;
  const int N = in_sizes[0] / F;
  const int E = in_sizes[1];
  const int C = in_sizes[10];   // = 10

  const int Fp = (F + 31) & ~31;           // 512
  const int Cp = (C + 31) & ~31;           // 32
  const int dims[8][2] = { {F,H},{H,H},{H,H},{H,C},{C,H},{H,H},{H,H},{H,F} };

  // ---- workspace layout (256B aligned)
  char* ws = (char*)d_ws;
  size_t off = 0;
  auto alloc = [&](size_t bytes) {
    void* p = ws + off;
    off += (bytes + 255) & ~(size_t)255;
    return p;
  };
  int*   deg       = (int*)alloc((size_t)N * 4);
  int*   row_start = (int*)alloc((size_t)(N + 1) * 4);
  int*   cursor    = (int*)alloc((size_t)N * 4);
  float* dinv      = (float*)alloc((size_t)N * 4);
  int*   part      = (int*)alloc(1024 * 4);
  int2*  csr_ent   = (int2*)alloc((size_t)E * 8);
  unsigned short* xb = (unsigned short*)alloc((size_t)N * Fp * 2);
  WtPack wp;
  for (int i = 0; i < 8; ++i) {
    wp.W[i] = Wp[i];
    wp.K[i] = dims[i][0];
    wp.Nd[i] = dims[i][1];
    wp.Kp[i] = (dims[i][0] + 31) & ~31;
    wp.Ndp[i] = (dims[i][1] + 127) & ~127;
    wp.Wt[i] = (unsigned short*)alloc((size_t)wp.Ndp[i] * wp.Kp[i] * 2);
  }
  unsigned short* hb   = (unsigned short*)alloc((size_t)N * H * 2);
  unsigned short* actP = (unsigned short*)alloc((size_t)N * H * 2);
  unsigned short* actQ = (unsigned short*)alloc((size_t)N * H * 2);
  unsigned short* zpre = (unsigned short*)alloc((size_t)N * 12 * 2);
  unsigned short* zenb = (unsigned short*)alloc((size_t)N * 12 * 2);
  unsigned short* zagg = (unsigned short*)alloc((size_t)N * Cp * 2);
  (void)ws_size;

  // ---- d_out: x_de[N,F] | enc_h1[N,H] | enc_h2[N,H] | enc_h3[N,H] | z_en[N,C]
  float* out_f  = (float*)d_out;
  float* o_xde  = out_f;
  float* o_enc1 = out_f + (size_t)N * F;
  float* o_enc2 = o_enc1 + (size_t)N * H;
  float* o_enc3 = o_enc2 + (size_t)N * H;
  float* o_zen  = o_enc3 + (size_t)N * H;

  const int T = 256;
  const int nb = (N + 255) / 256;
  // ---- graph preprocessing
  k_zero_int<<<(N + T - 1) / T, T, 0, stream>>>(deg, N);
  k_deg<<<(E + T - 1) / T, T, 0, stream>>>(dst, deg, E);
  k_scan1<<<nb, 256, 0, stream>>>(deg, part, N);
  k_scan2<<<1, 1024, 0, stream>>>(part, nb);
  k_scan3<<<nb, 256, 0, stream>>>(deg, part, row_start, cursor, dinv, N);
  k_fill_csr<<<(E + T - 1) / T, T, 0, stream>>>(src, dst, dinv, cursor, csr_ent, E);
  // ---- conversions
  {
    int nth = N * (Fp >> 3);
    k_cvt_pad<<<(nth + T - 1) / T, T, 0, stream>>>(x, xb, N, F, Fp);
    int maxElems = 0;
    for (int i = 0; i < 8; ++i) {
      int e = wp.Kp[i] * wp.Ndp[i];
      if (e > maxElems) maxElems = e;
    }
    dim3 g((maxElems + T - 1) / T, 8);
    k_wt_all<<<g, T, 0, stream>>>(wp);
  }

  auto gemm = [&](const unsigned short* A, int lda, int widx, const float* bias,
                  float* Cf, int ldcf, unsigned short* Cb, int ldcb,
                  int Nd, int relu) {
    dim3 grid((N + 127) / 128, (Nd + 127) / 128);
    gemm_bf16<<<grid, 256, 0, stream>>>(A, wp.Wt[widx], bias, Cf, ldcf, Cb, ldcb,
                                        N, wp.Kp[widx], Nd, lda, relu);
  };
  auto agg256 = [&](const unsigned short* h, const float* bias, float* Of,
                    unsigned short* Ob, int relu) {
    agg_wave<<<(N + 3) / 4, 256, 0, stream>>>(h, row_start, csr_ent,
                                              dinv, bias, Of, Ob, N, relu);
  };

  // enc1: h = xb @ W0 ; enc_h1 = relu(agg(h)+b0)
  gemm(xb, Fp, 0, nullptr, nullptr, 0, hb, H, H, 0);
  agg256(hb, bp[0], o_enc1, actP, 1);
  // enc2
  gemm(actP, H, 1, nullptr, nullptr, 0, hb, H, H, 0);
  agg256(hb, bp[1], o_enc2, actQ, 1);
  // enc3
  gemm(actQ, H, 2, nullptr, nullptr, 0, hb, H, H, 0);
  agg256(hb, bp[2], o_enc3, actP, 1);
  // zen: zpre = enc_h3 @ W3 (ld 12) ; z_en = agg(zpre) + b3
  gemm(actP, H, 3, nullptr, nullptr, 0, zpre, 12, C, 0);
  agg_code<10><<<(N + T - 1) / T, T, 0, stream>>>(
      zpre, row_start, csr_ent, dinv, bp[3], o_zen, zenb, 12, N);
  // dec1 (linearity): zagg = agg_nobias(z_en) ; d1 = relu(zagg @ W4 + b4)
  agg_code<10><<<(N + T - 1) / T, T, 0, stream>>>(
      zenb, row_start, csr_ent, dinv, nullptr, nullptr, zagg, Cp, N);
  gemm(zagg, Cp, 4, bp[4], nullptr, 0, actQ, H, H, 1);
  // dec2
  gemm(actQ, H, 5, nullptr, nullptr, 0, hb, H, H, 0);
  agg256(hb, bp[5], nullptr, actP, 1);
  // dec3
  gemm(actP, H, 6, nullptr, nullptr, 0, hb, H, H, 0);
  agg256(hb, bp[6], nullptr, actQ, 1);
  // xde (linearity): dagg = agg_nobias(d3) ; x_de = dagg @ W7 + b7 (fp32)
  agg256(actQ, nullptr, nullptr, actP, 0);
  gemm(actP, H, 7, bp[7], o_xde, F, nullptr, 0, F, 0);
}